// Round 10
// baseline (207.749 us; speedup 1.0000x reference)
//
#include <hip/hip_runtime.h>
#include <hip/hip_cooperative_groups.h>
#include <math.h>

namespace cg = cooperative_groups;

#define NPT 2048
#define KNN 20

typedef const float* fp;
typedef __attribute__((ext_vector_type(4))) float f32x4;
typedef __attribute__((ext_vector_type(8))) short s16x8;

// round-to-nearest-even f32 -> bf16 bits (inputs are finite)
__device__ __forceinline__ ushort f2bf_rne(float v) {
    unsigned u = __float_as_uint(v);
    unsigned r = u + 0x7FFFu + ((u >> 16) & 1u);
    return (ushort)(r >> 16);
}
__device__ __forceinline__ float bfbits2f(ushort h) {
    return __uint_as_float(((unsigned)h) << 16);
}
__device__ __forceinline__ s16x8 ldfrag(const ushort* p) {
    union { uint4 u; s16x8 s; } cv;
    cv.u = *reinterpret_cast<const uint4*>(p);
    return cv.s;
}
// 8 consecutive f32 -> bf16 hi/lo fragment pair (in-register fragify)
__device__ __forceinline__ void f8_hilo(const float* row, s16x8* hi, s16x8* lo) {
    float4 f0 = *reinterpret_cast<const float4*>(row);
    float4 f1 = *reinterpret_cast<const float4*>(row + 4);
    float f[8] = {f0.x, f0.y, f0.z, f0.w, f1.x, f1.y, f1.z, f1.w};
    union { ushort u[8]; s16x8 s; } H, L;
    #pragma unroll
    for (int j = 0; j < 8; j++) {
        ushort h = f2bf_rne(f[j]);
        H.u[j] = h;
        L.u[j] = f2bf_rne(f[j] - bfbits2f(h));
    }
    *hi = H.s; *lo = L.s;
}

// ---------------------------------------------------------------------------
// prep_all: blocks [0,256) = fragify x + xx; blocks [256,835) = weight frags
//   (q/k/v K=128; wc=[w1x | w1a@wm] K=256 on-the-fly; w2 K=256), b1p, stats=0.
// ---------------------------------------------------------------------------
__global__ __launch_bounds__(256) void prep_all(
    fp xbf, fp wq, fp wk, fp wv, fp wm, fp w1, fp w2, fp bm, fp b1,
    float* xx, ushort* xhiF, ushort* xloF,
    ushort* wqFhi, ushort* wqFlo, ushort* wkFhi, ushort* wkFlo,
    ushort* wvFhi, ushort* wvFlo,
    ushort* wcFhi, ushort* wcFlo, ushort* w2Fhi, ushort* w2Flo,
    float* b1p, float* stats) {
    int t = threadIdx.x;
    if (blockIdx.x < 256) {                 // ---- x frags + xx ----
        __shared__ float xs[16][129];
        __shared__ float xpart[16][17];
        int p0 = blockIdx.x * 16;
        int b = p0 >> 11, n0 = p0 & 2047;
        fp xb = xbf + (size_t)b * 128 * NPT;
        {
            int c = t >> 1, half = t & 1;
            float4 f0 = *reinterpret_cast<const float4*>(xb + (size_t)c * NPT + n0 + half * 8);
            float4 f1 = *reinterpret_cast<const float4*>(xb + (size_t)c * NPT + n0 + half * 8 + 4);
            xs[half * 8 + 0][c] = f0.x; xs[half * 8 + 1][c] = f0.y;
            xs[half * 8 + 2][c] = f0.z; xs[half * 8 + 3][c] = f0.w;
            xs[half * 8 + 4][c] = f1.x; xs[half * 8 + 5][c] = f1.y;
            xs[half * 8 + 6][c] = f1.z; xs[half * 8 + 7][c] = f1.w;
        }
        __syncthreads();
        int p = t & 15, g = t >> 4, c0 = g * 8;
        float f[8];
        #pragma unroll
        for (int j = 0; j < 8; j++) f[j] = xs[p][c0 + j];
        float ps = 0.f;
        #pragma unroll
        for (int j = 0; j < 8; j++) ps += f[j] * f[j];
        xpart[p][g] = ps;
        union { ushort u[8]; uint4 q; } H, L;
        #pragma unroll
        for (int j = 0; j < 8; j++) {
            ushort hi = f2bf_rne(f[j]);
            H.u[j] = hi;
            L.u[j] = f2bf_rne(f[j] - bfbits2f(hi));
        }
        size_t off = ((size_t)blockIdx.x * 4 + (c0 >> 5)) * 512
                   + (size_t)(((((c0 >> 3) & 3) * 16) + p) * 8);
        *reinterpret_cast<uint4*>(xhiF + off) = H.q;
        *reinterpret_cast<uint4*>(xloF + off) = L.q;
        __syncthreads();
        if (t < 16) {
            float s = 0.f;
            #pragma unroll
            for (int gg = 0; gg < 16; gg++) s += xpart[t][gg];
            xx[p0 + t] = s;
        }
        return;
    }
    int wid = (blockIdx.x - 256) * 256 + t;
    if (wid < 49152) {                      // q/k/v frags (K=128)
        int which = wid >> 14, e = wid & 16383;
        int lane = (e >> 3) & 63, j = e & 7, kk = (e >> 9) & 3, nt = e >> 11;
        int n = nt * 16 + (lane & 15);
        int k = kk * 32 + (lane >> 4) * 8 + j;
        fp src = which == 0 ? wq : which == 1 ? wk : wv;
        float v = src[n * 128 + k];
        ushort hi = f2bf_rne(v);
        (which == 0 ? wqFhi : which == 1 ? wkFhi : wvFhi)[e] = hi;
        (which == 0 ? wqFlo : which == 1 ? wkFlo : wvFlo)[e] = f2bf_rne(v - bfbits2f(hi));
    } else if (wid < 114688) {              // wc frags (N=256, K=256)
        int e = wid - 49152;
        int j = e & 7, lane = (e >> 3) & 63, kk = (e >> 9) & 7, nt = e >> 12;
        int n = nt * 16 + (lane & 15);
        int k = kk * 32 + (lane >> 4) * 8 + j;
        float v;
        if (k < 128) {
            v = w1[n * 256 + k];
        } else {                            // W[n][k-128] = w1a@wm on the fly
            int c = k - 128;
            float s = 0.f;
            for (int i = 0; i < 128; i += 4) {
                float4 wr = *reinterpret_cast<const float4*>(w1 + n * 256 + 128 + i);
                s += wr.x * wm[(i + 0) * 128 + c];
                s += wr.y * wm[(i + 1) * 128 + c];
                s += wr.z * wm[(i + 2) * 128 + c];
                s += wr.w * wm[(i + 3) * 128 + c];
            }
            v = s;
        }
        ushort hi = f2bf_rne(v);
        wcFhi[e] = hi;
        wcFlo[e] = f2bf_rne(v - bfbits2f(hi));
    } else if (wid < 147456) {              // w2 frags (N=128, K=256)
        int e = wid - 114688;
        int j = e & 7, lane = (e >> 3) & 63, kk = (e >> 9) & 7, nt = e >> 12;
        int n = nt * 16 + (lane & 15);
        int k = kk * 32 + (lane >> 4) * 8 + j;
        float v = w2[n * 256 + k];
        ushort hi = f2bf_rne(v);
        w2Fhi[e] = hi;
        w2Flo[e] = f2bf_rne(v - bfbits2f(hi));
    } else if (wid < 147712) {              // b1p = b1 + w1a@bm
        int o = wid - 147456;
        float s = b1[o];
        for (int i = 0; i < 128; i++)
            s += w1[o * 256 + 128 + i] * bm[i];
        b1p[o] = s;
    } else {                                // BN stats zero (512)
        stats[wid - 147712] = 0.0f;
    }
}

// ---------------------------------------------------------------------------
// gemm_key_topk v8: qkv + key GEMM + exact in-kernel top-20 (unchanged r9).
// ---------------------------------------------------------------------------
#define MERGE(off) { float ov = __shfl_xor(bv, off); int oi = __shfl_xor(bi, off); \
                     if (ov > bv || (ov == bv && oi < bi)) { bv = ov; bi = oi; } }

#define KEYPAIR(C0, D0, D1) { \
    int ct0 = slab * 128 + w * 8 + C0; \
    int ct1 = ct0 + 1; \
    f32x4 a0 = (f32x4){0.f, 0.f, 0.f, 0.f}; \
    f32x4 a1 = (f32x4){0.f, 0.f, 0.f, 0.f}; \
    _Pragma("unroll 2") \
    for (int kk = 0; kk < 4; kk++) { \
        s16x8 ah = ldfrag(Ahi[kk] + lane * 8); \
        s16x8 al = ldfrag(Alo[kk] + lane * 8); \
        s16x8 b0h = ldfrag(xhiF + ((size_t)(ct0 * 4 + kk)) * 512 + lane * 8); \
        s16x8 b0l = ldfrag(xloF + ((size_t)(ct0 * 4 + kk)) * 512 + lane * 8); \
        s16x8 b1h = ldfrag(xhiF + ((size_t)(ct1 * 4 + kk)) * 512 + lane * 8); \
        s16x8 b1l = ldfrag(xloF + ((size_t)(ct1 * 4 + kk)) * 512 + lane * 8); \
        a0 = __builtin_amdgcn_mfma_f32_16x16x32_bf16(ah, b0h, a0, 0, 0, 0); \
        a1 = __builtin_amdgcn_mfma_f32_16x16x32_bf16(ah, b1h, a1, 0, 0, 0); \
        a0 = __builtin_amdgcn_mfma_f32_16x16x32_bf16(al, b0h, a0, 0, 0, 0); \
        a1 = __builtin_amdgcn_mfma_f32_16x16x32_bf16(al, b1h, a1, 0, 0, 0); \
        a0 = __builtin_amdgcn_mfma_f32_16x16x32_bf16(ah, b0l, a0, 0, 0, 0); \
        a1 = __builtin_amdgcn_mfma_f32_16x16x32_bf16(ah, b1l, a1, 0, 0, 0); \
    } \
    float xx0 = xx[slab * 2048 + (w * 8 + C0) * 16 + cl]; \
    float xx1 = xx[slab * 2048 + (w * 8 + C0 + 1) * 16 + cl]; \
    a0[0] = 2.0f * a0[0] - xx0; a0[1] = 2.0f * a0[1] - xx0; \
    a0[2] = 2.0f * a0[2] - xx0; a0[3] = 2.0f * a0[3] - xx0; \
    a1[0] = 2.0f * a1[0] - xx1; a1[1] = 2.0f * a1[1] - xx1; \
    a1[2] = 2.0f * a1[2] - xx1; a1[3] = 2.0f * a1[3] - xx1; \
    D0 = a0; D1 = a1; \
}

__global__ __launch_bounds__(1024, 4) void gemm_key_topk(
    const ushort* xhiF, const ushort* xloF, const float* xx,
    const ushort* wqFhi, const ushort* wqFlo,
    const ushort* wkFhi, const ushort* wkFlo,
    const ushort* wvFhi, const ushort* wvFlo,
    fp bq, fp bk, fp bv_, float* qT, float* kT, float* vT,
    int* idxbuf, float* scratch) {
    __shared__ ushort Ahi[4][512];          // 4 KB  A-frags hi [kk][lane*8]
    __shared__ ushort Alo[4][512];          // 4 KB  A-frags lo
    __shared__ float chm[16][64];           // 4 KB  per-row chunk maxima
    __shared__ float sv[16][256];           // 16 KB survivor values
    __shared__ int   si[16][256];           // 16 KB survivor cols
    __shared__ float Trow[16];
    __shared__ int   rowcnt[16];
    __shared__ int   ovfAll;
    int tt = threadIdx.x, w = tt >> 6, lane = tt & 63;
    int rt = blockIdx.x;                    // row-tile 0..255
    int slab = rt >> 7, rtl = rt & 127;
    int cl = lane & 15, quad = lane >> 4;

    if (tt < 16) rowcnt[tt] = 0;

    // ---- stage A-frags to LDS (512 threads x 16B = 8 KB) ----
    if (tt < 512) {
        int which = tt >> 8, kk = (tt >> 6) & 3, ln = tt & 63;
        const ushort* src = (which ? xloF : xhiF)
                          + ((size_t)(rt * 4 + kk)) * 512 + ln * 8;
        uint4 v = *reinterpret_cast<const uint4*>(src);
        *reinterpret_cast<uint4*>((which ? Alo[kk] : Ahi[kk]) + ln * 8) = v;
    }
    __syncthreads();

    // ---- Phase 1: qkv (24 (mat,nt) pairs; waves 0..11 take 2 each) ----
    if (w < 12) {
        f32x4 acc0 = (f32x4){0.f, 0.f, 0.f, 0.f};
        f32x4 acc1 = (f32x4){0.f, 0.f, 0.f, 0.f};
        int pair0 = w * 2, pair1 = w * 2 + 1;
        int mat0 = pair0 >> 3, nt0 = pair0 & 7;
        int mat1 = pair1 >> 3, nt1 = pair1 & 7;
        const ushort* w0hi = mat0 == 0 ? wqFhi : mat0 == 1 ? wkFhi : wvFhi;
        const ushort* w0lo = mat0 == 0 ? wqFlo : mat0 == 1 ? wkFlo : wvFlo;
        const ushort* w1hi = mat1 == 0 ? wqFhi : mat1 == 1 ? wkFhi : wvFhi;
        const ushort* w1lo = mat1 == 0 ? wqFlo : mat1 == 1 ? wkFlo : wvFlo;
        #pragma unroll 2
        for (int kk = 0; kk < 4; kk++) {
            s16x8 ah = ldfrag(Ahi[kk] + lane * 8);
            s16x8 al = ldfrag(Alo[kk] + lane * 8);
            s16x8 b0h = ldfrag(w0hi + ((size_t)(nt0 * 4 + kk)) * 512 + lane * 8);
            s16x8 b0l = ldfrag(w0lo + ((size_t)(nt0 * 4 + kk)) * 512 + lane * 8);
            s16x8 b1h = ldfrag(w1hi + ((size_t)(nt1 * 4 + kk)) * 512 + lane * 8);
            s16x8 b1l = ldfrag(w1lo + ((size_t)(nt1 * 4 + kk)) * 512 + lane * 8);
            acc0 = __builtin_amdgcn_mfma_f32_16x16x32_bf16(ah, b0h, acc0, 0, 0, 0);
            acc1 = __builtin_amdgcn_mfma_f32_16x16x32_bf16(ah, b1h, acc1, 0, 0, 0);
            acc0 = __builtin_amdgcn_mfma_f32_16x16x32_bf16(al, b0h, acc0, 0, 0, 0);
            acc1 = __builtin_amdgcn_mfma_f32_16x16x32_bf16(al, b1h, acc1, 0, 0, 0);
            acc0 = __builtin_amdgcn_mfma_f32_16x16x32_bf16(ah, b0l, acc0, 0, 0, 0);
            acc1 = __builtin_amdgcn_mfma_f32_16x16x32_bf16(ah, b1l, acc1, 0, 0, 0);
        }
        int p0 = rt * 16;
        {
            fp bias    = mat0 == 0 ? bq : mat0 == 1 ? bk : bv_;
            float* out = mat0 == 0 ? qT : mat0 == 1 ? kT : vT;
            int o = nt0 * 16 + cl;
            float bvv = bias[o];
            #pragma unroll
            for (int r = 0; r < 4; r++)
                out[(size_t)(p0 + quad * 4 + r) * 128 + o] = acc0[r] + bvv;
        }
        {
            fp bias    = mat1 == 0 ? bq : mat1 == 1 ? bk : bv_;
            float* out = mat1 == 0 ? qT : mat1 == 1 ? kT : vT;
            int o = nt1 * 16 + cl;
            float bvv = bias[o];
            #pragma unroll
            for (int r = 0; r < 4; r++)
                out[(size_t)(p0 + quad * 4 + r) * 128 + o] = acc1[r] + bvv;
        }
    }
    __builtin_amdgcn_sched_barrier(0);

    // ---- Phase 2: key GEMM, 8 named regs, 4 ILP-pairs ----
    f32x4 key0, key1, key2, key3, key4, key5, key6, key7;
    KEYPAIR(0, key0, key1)
    __builtin_amdgcn_sched_barrier(0);
    KEYPAIR(2, key2, key3)
    __builtin_amdgcn_sched_barrier(0);
    KEYPAIR(4, key4, key5)
    __builtin_amdgcn_sched_barrier(0);
    KEYPAIR(6, key6, key7)
    __builtin_amdgcn_sched_barrier(0);

    // ---- chunk maxima: chunks of 32 cols (8 c-tiles x 4 cl); 64/row ----
    {
        float m[4];
        #pragma unroll
        for (int r = 0; r < 4; r++) {
            float mm = fmaxf(fmaxf(fmaxf(key0[r], key1[r]), fmaxf(key2[r], key3[r])),
                             fmaxf(fmaxf(key4[r], key5[r]), fmaxf(key6[r], key7[r])));
            mm = fmaxf(mm, __shfl_xor(mm, 1));
            mm = fmaxf(mm, __shfl_xor(mm, 2));
            m[r] = mm;
        }
        if ((cl & 3) == 0) {
            #pragma unroll
            for (int r = 0; r < 4; r++)
                chm[quad * 4 + r][w * 4 + (cl >> 2)] = m[r];
        }
    }
    __syncthreads();

    // ---- per-row threshold: wave w sorts row w's 64 chunk maxima ----
    {
        float bs = chm[w][lane];
        #pragma unroll
        for (int k = 2; k <= 64; k <<= 1) {
            #pragma unroll
            for (int j = k >> 1; j > 0; j >>= 1) {
                float o = __shfl_xor(bs, j);
                bool dirDesc = (lane & k) != 0;
                bool upper   = (lane & j) != 0;
                bs = (upper != dirDesc) ? fmaxf(bs, o) : fminf(bs, o);
            }
        }
        float T = __shfl(bs, 44);           // 20th largest chunk max <= v20
        if (lane == 0) Trow[w] = T;
    }
    __syncthreads();

    // ---- survivor compaction (atomic append per row) ----
    #pragma unroll
    for (int r = 0; r < 4; r++) {
        int row = quad * 4 + r;
        float T = Trow[row];
        float vals[8] = {key0[r], key1[r], key2[r], key3[r],
                         key4[r], key5[r], key6[r], key7[r]};
        #pragma unroll
        for (int c = 0; c < 8; c++) {
            float v = vals[c];
            if (v >= T) {
                int pos = atomicAdd(&rowcnt[row], 1);
                if (pos < 256) {
                    sv[row][pos] = v;
                    si[row][pos] = (w * 8 + c) * 16 + cl;
                }
            }
        }
    }
    __syncthreads();
    if (tt == 0) {
        int o = 0;
        for (int i = 0; i < 16; i++) o |= (rowcnt[i] > 256) ? 1 : 0;
        ovfAll = o;
    }
    __syncthreads();
    int ovf = ovfAll;

    // ---- in-kernel final selection: wave w owns row w ----
    int S = rowcnt[w];
    int rowg = slab * 2048 + rtl * 16 + w;
    if (S <= 64) {                          // common case (S>=20 guaranteed)
        float v; int idx;
        if (lane < S) { v = sv[w][lane]; idx = si[w][lane]; }
        else          { v = -3.4e38f;    idx = 0x7FFFFFFF; }
        #pragma unroll
        for (int k = 2; k <= 64; k <<= 1) {
            #pragma unroll
            for (int j = k >> 1; j > 0; j >>= 1) {
                float ov = __shfl_xor(v, j); int oi = __shfl_xor(idx, j);
                bool dirDesc = (lane & k) != 0;
                bool upper   = (lane & j) != 0;
                bool takeMax = (upper != dirDesc);
                bool amax = (v > ov) || (v == ov && idx < oi);
                if (takeMax != amax) { v = ov; idx = oi; }
            }
        }
        if (lane >= 44) idxbuf[(size_t)rowg * KNN + (63 - lane)] = idx;
    } else if (S <= 256) {                  // exact iterative extract
        float vl[4]; int il[4];
        #pragma unroll
        for (int s = 0; s < 4; s++) {
            int g = lane + s * 64;
            bool ok = g < S;
            vl[s] = ok ? sv[w][g] : -3.4e38f;
            il[s] = ok ? si[w][g] : 0x7FFFFFFF;
        }
        unsigned removed = 0u;
        for (int iter = 0; iter < KNN; iter++) {
            float bv = -3.4e38f; int bi = 0x7FFFFFFF;
            #pragma unroll
            for (int s = 0; s < 4; s++) {
                bool live = ((removed >> s) & 1u) == 0u;
                if (live && (vl[s] > bv || (vl[s] == bv && il[s] < bi))) {
                    bv = vl[s]; bi = il[s];
                }
            }
            MERGE(32) MERGE(16) MERGE(8) MERGE(4) MERGE(2) MERGE(1)
            if (lane == 0) idxbuf[(size_t)rowg * KNN + iter] = bi;
            #pragma unroll
            for (int s = 0; s < 4; s++)     // indices unique: safe removal
                if (il[s] == bi) removed |= 1u << s;
        }
    }

    // ---- exact overflow fallback (never expected; correctness only) ----
    if (ovf) {
        #pragma unroll
        for (int r = 0; r < 4; r++) {
            float vals[8] = {key0[r], key1[r], key2[r], key3[r],
                             key4[r], key5[r], key6[r], key7[r]};
            #pragma unroll
            for (int c = 0; c < 8; c++)
                scratch[((size_t)rt * 16 + quad * 4 + r) * 2048
                        + (w * 8 + c) * 16 + cl] = vals[c];
        }
        __syncthreads();
        if (rowcnt[w] > 256) {
            const float* rowp = scratch + ((size_t)rt * 16 + w) * 2048;
            float rv[32];
            #pragma unroll
            for (int j = 0; j < 32; j++) rv[j] = rowp[j * 64 + lane];
            unsigned removed = 0u;
            for (int iter = 0; iter < KNN; iter++) {
                float bv = -3.4e38f; int bi = 0;
                #pragma unroll
                for (int sl = 0; sl < 32; sl++) {
                    bool live = ((removed >> sl) & 1u) == 0u;
                    if (live && rv[sl] > bv) { bv = rv[sl]; bi = sl * 64 + lane; }
                }
                MERGE(32) MERGE(16) MERGE(8) MERGE(4) MERGE(2) MERGE(1)
                if (lane == 0) idxbuf[(size_t)rowg * KNN + iter] = bi;
                if ((bi & 63) == lane) removed |= 1u << (bi >> 6);
            }
        }
    }
}

// ---------------------------------------------------------------------------
// k345_fused: cooperative kernel, 256 blocks x 1024 threads (block rt owns
//   points p0..p0+15).
//   Phase K3 (2 passes x 8 subgroups of 128 threads): mutual-KNN attention;
//     avT rows stay in LDS (avL, rows padded to 132 floats: bank-spread).
//   Phase A (k4b): stage x-frags + fragify avL once; wave w computes nt=w;
//     h rows stay in LDS (Hb, padded to 260); BN stats via global atomics.
//   grid.sync()  — the ONLY global dependency (BN stats over all points).
//   Phase B (k5b): BN+relu+fragify from Hb (waves 0-7, kk=w); wave w
//     computes nt=w; out = w2@relu(BN(h)) + b2 + x.
//   All MFMA chains / conversions identical to the split kernels ->
//   bit-identical output. Removes avT+hbuf HBM round-trips (12 MB) and two
//   launch/drain boundaries.
// ---------------------------------------------------------------------------
__global__ __launch_bounds__(1024) void k345_fused(
    fp qT, fp kT, fp vT, const int* idxbuf,
    const ushort* xhiF, const ushort* xloF,
    const ushort* wcFhi, const ushort* wcFlo,
    const float* b1p, float* stats,
    fp gamma, fp beta,
    const ushort* w2Fhi, const ushort* w2Flo,
    fp b2, fp xbf, float* out) {
    __shared__ ushort AH[8][512];           // 8 KB; reused as HH in phase B
    __shared__ ushort AL[8][512];           // 8 KB; reused as HL in phase B
    __shared__ float avL[16][132];          // 8.4 KB (padded rows)
    __shared__ float Hb[16][260];           // 16.6 KB (padded rows)
    __shared__ float sbuf[8][KNN * 4];
    __shared__ int   mlist[8][KNN];
    __shared__ int   cnt_s[8];
    int tt = threadIdx.x, w = tt >> 6, lane = tt & 63;
    int rt = blockIdx.x;                    // 0..255
    int p0 = rt * 16;
    int cl = lane & 15, quad = lane >> 4;

    // ================= Phase K3: 16 points, 2 passes of 8 ==================
    for (int pass = 0; pass < 2; pass++) {
        int sg = tt >> 7, t = tt & 127;
        int pl = pass * 8 + sg;
        int p = p0 + pl;
        int b = p >> 11, n = p & 2047;
        int bbase = b * NPT;
        int h = t >> 5;

        if ((t >> 6) == 0) {                // first wave of each subgroup
            int ln = tt & 63;
            bool fl = false; int m = 0;
            if (ln < KNN) {
                m = idxbuf[(size_t)p * KNN + ln] & 2047;
                const int4* mrow = reinterpret_cast<const int4*>(idxbuf + (size_t)(bbase + m) * KNN);
                int4 r0 = mrow[0], r1 = mrow[1], r2 = mrow[2], r3 = mrow[3], r4 = mrow[4];
                fl = (r0.x == n) || (r0.y == n) || (r0.z == n) || (r0.w == n)
                  || (r1.x == n) || (r1.y == n) || (r1.z == n) || (r1.w == n)
                  || (r2.x == n) || (r2.y == n) || (r2.z == n) || (r2.w == n)
                  || (r3.x == n) || (r3.y == n) || (r3.z == n) || (r3.w == n)
                  || (r4.x == n) || (r4.y == n) || (r4.z == n) || (r4.w == n);
            }
            unsigned long long mask = __ballot(fl);
            int pos = __popcll(mask & ((1ull << ln) - 1ull));
            if (fl) mlist[sg][pos] = m;
            if (ln == 0) cnt_s[sg] = (int)__popcll(mask);
        }
        __syncthreads();

        int cnt = cnt_s[sg];
        float qv = qT[(size_t)p * 128 + t];
        int jj = 0;
        for (; jj + 1 < cnt; jj += 2) {
            int m0 = mlist[sg][jj], m1 = mlist[sg][jj + 1];
            float pr0 = qv * kT[(size_t)(bbase + m0) * 128 + t];
            float pr1 = qv * kT[(size_t)(bbase + m1) * 128 + t];
            pr0 += __shfl_xor(pr0, 16); pr1 += __shfl_xor(pr1, 16);
            pr0 += __shfl_xor(pr0, 8);  pr1 += __shfl_xor(pr1, 8);
            pr0 += __shfl_xor(pr0, 4);  pr1 += __shfl_xor(pr1, 4);
            pr0 += __shfl_xor(pr0, 2);  pr1 += __shfl_xor(pr1, 2);
            pr0 += __shfl_xor(pr0, 1);  pr1 += __shfl_xor(pr1, 1);
            if ((t & 31) == 0) {
                sbuf[sg][jj * 4 + h]       = pr0 * 0.17677669529663687f;
                sbuf[sg][(jj + 1) * 4 + h] = pr1 * 0.17677669529663687f;
            }
        }
        if (jj < cnt) {
            int m = mlist[sg][jj];
            float prod = qv * kT[(size_t)(bbase + m) * 128 + t];
            prod += __shfl_xor(prod, 16);
            prod += __shfl_xor(prod, 8);
            prod += __shfl_xor(prod, 4);
            prod += __shfl_xor(prod, 2);
            prod += __shfl_xor(prod, 1);
            if ((t & 31) == 0) sbuf[sg][jj * 4 + h] = prod * 0.17677669529663687f;
        }
        __syncthreads();

        float mx = -3.4e38f;
        for (int j = 0; j < cnt; j++) mx = fmaxf(mx, sbuf[sg][j * 4 + h]);
        float den = 0.f, accv = 0.f;
        for (int j = 0; j < cnt; j++) {
            float ex = expf(sbuf[sg][j * 4 + h] - mx);
            den += ex;
            accv += ex * vT[(size_t)(bbase + mlist[sg][j]) * 128 + t];
        }
        float inv = (cnt > 0) ? (1.0f / den) : 0.0f;
        avL[pl][t] = accv * inv;
        __syncthreads();                    // protect sbuf/mlist reuse + avL
    }

    // ================= Phase A: k4b (h into LDS + stats) ===================
    if (w < 8) {
        int which = w & 1, kk = w >> 1;
        const ushort* src = (which ? xloF : xhiF)
                          + ((size_t)(rt * 4 + kk)) * 512 + lane * 8;
        uint4 v = *reinterpret_cast<const uint4*>(src);
        *reinterpret_cast<uint4*>((which ? AL[kk] : AH[kk]) + lane * 8) = v;
    } else if (w < 12) {
        int kk = 4 + (w - 8);
        const float* arow = &avL[lane & 15][(kk - 4) * 32 + (lane >> 4) * 8];
        s16x8 hi, lo;
        f8_hilo(arow, &hi, &lo);
        union { s16x8 s; uint4 u; } cvh, cvl;
        cvh.s = hi; cvl.s = lo;
        *reinterpret_cast<uint4*>(AH[kk] + lane * 8) = cvh.u;
        *reinterpret_cast<uint4*>(AL[kk] + lane * 8) = cvl.u;
    }
    __syncthreads();

    {
        int nt = w;                         // 16 waves, 16 nt tiles
        f32x4 acc = (f32x4){0.f, 0.f, 0.f, 0.f};
        for (int kk = 0; kk < 8; kk++) {
            s16x8 ahi = ldfrag(AH[kk] + lane * 8);
            s16x8 alo = ldfrag(AL[kk] + lane * 8);
            s16x8 bhi = ldfrag(wcFhi + ((size_t)(nt * 8 + kk)) * 512 + lane * 8);
            s16x8 blo = ldfrag(wcFlo + ((size_t)(nt * 8 + kk)) * 512 + lane * 8);
            acc = __builtin_amdgcn_mfma_f32_16x16x32_bf16(ahi, bhi, acc, 0, 0, 0);
            acc = __builtin_amdgcn_mfma_f32_16x16x32_bf16(alo, bhi, acc, 0, 0, 0);
            acc = __builtin_amdgcn_mfma_f32_16x16x32_bf16(ahi, blo, acc, 0, 0, 0);
        }
        int o = nt * 16 + cl;
        float bb = b1p[o];
        float s = 0.f, s2 = 0.f;
        #pragma unroll
        for (int r = 0; r < 4; r++) {
            float v = acc[r] + bb;
            Hb[quad * 4 + r][o] = v;
            s += v; s2 += v * v;
        }
        s  += __shfl_xor(s, 16);  s  += __shfl_xor(s, 32);
        s2 += __shfl_xor(s2, 16); s2 += __shfl_xor(s2, 32);
        if (quad == 0) {
            atomicAdd(&stats[o], s);
            atomicAdd(&stats[256 + o], s2);
        }
    }

    cg::this_grid().sync();                 // BN stats complete device-wide

    // ================= Phase B: k5b (BN + out GEMM) ========================
    if (w < 8) {                            // stage: wave w converts kk=w
        int kk = w;
        int c0 = kk * 32 + (lane >> 4) * 8;
        const float* hrow = &Hb[lane & 15][c0];
        float4 f0 = *reinterpret_cast<const float4*>(hrow);
        float4 f1 = *reinterpret_cast<const float4*>(hrow + 4);
        float4 s0 = *reinterpret_cast<const float4*>(stats + c0);
        float4 s1 = *reinterpret_cast<const float4*>(stats + c0 + 4);
        float4 q0 = *reinterpret_cast<const float4*>(stats + 256 + c0);
        float4 q1 = *reinterpret_cast<const float4*>(stats + 256 + c0 + 4);
        float4 g0 = *reinterpret_cast<const float4*>(gamma + c0);
        float4 g1 = *reinterpret_cast<const float4*>(gamma + c0 + 4);
        float4 e0 = *reinterpret_cast<const float4*>(beta + c0);
        float4 e1 = *reinterpret_cast<const float4*>(beta + c0 + 4);
        float f[8] = {f0.x, f0.y, f0.z, f0.w, f1.x, f1.y, f1.z, f1.w};
        float sm[8] = {s0.x, s0.y, s0.z, s0.w, s1.x, s1.y, s1.z, s1.w};
        float sq[8] = {q0.x, q0.y, q0.z, q0.w, q1.x, q1.y, q1.z, q1.w};
        float gm[8] = {g0.x, g0.y, g0.z, g0.w, g1.x, g1.y, g1.z, g1.w};
        float bt[8] = {e0.x, e0.y, e0.z, e0.w, e1.x, e1.y, e1.z, e1.w};
        union { ushort u[8]; uint4 q; } H, L;
        #pragma unroll
        for (int j = 0; j < 8; j++) {
            float mu  = sm[j] * (1.0f / 4096.0f);
            float var = fmaxf(sq[j] * (1.0f / 4096.0f) - mu * mu, 0.0f);
            float a    = gm[j] / sqrtf(var + 1e-5f);
            float cadd = bt[j] - mu * a;
            float v = fmaxf(f[j] * a + cadd, 0.0f);
            ushort hi = f2bf_rne(v);
            H.u[j] = hi;
            L.u[j] = f2bf_rne(v - bfbits2f(hi));
        }
        *reinterpret_cast<uint4*>(AH[kk] + lane * 8) = H.q;   // HH
        *reinterpret_cast<uint4*>(AL[kk] + lane * 8) = L.q;   // HL
    }
    __syncthreads();

    if (w < 8) {                            // compute: wave w owns nt=w
        int nt = w;
        f32x4 acc = (f32x4){0.f, 0.f, 0.f, 0.f};
        for (int kk = 0; kk < 8; kk++) {
            s16x8 ahi = ldfrag(AH[kk] + lane * 8);
            s16x8 alo = ldfrag(AL[kk] + lane * 8);
            s16x8 bhi = ldfrag(w2Fhi + ((size_t)(nt * 8 + kk)) * 512 + lane * 8);
            s16x8 blo = ldfrag(w2Flo + ((size_t)(nt * 8 + kk)) * 512 + lane * 8);
            acc = __builtin_amdgcn_mfma_f32_16x16x32_bf16(ahi, bhi, acc, 0, 0, 0);
            acc = __builtin_amdgcn_mfma_f32_16x16x32_bf16(alo, bhi, acc, 0, 0, 0);
            acc = __builtin_amdgcn_mfma_f32_16x16x32_bf16(ahi, blo, acc, 0, 0, 0);
        }
        int b = p0 >> 11, n0 = p0 & 2047;
        int o = nt * 16 + cl;
        float bb = b2[o];
        size_t base = (size_t)b * 128 * NPT + (size_t)o * NPT + n0 + quad * 4;
        float4 xv = *reinterpret_cast<const float4*>(xbf + base);
        float4 ov;
        ov.x = acc[0] + bb + xv.x;
        ov.y = acc[1] + bb + xv.y;
        ov.z = acc[2] + bb + xv.z;
        ov.w = acc[3] + bb + xv.w;
        *reinterpret_cast<float4*>(out + base) = ov;
    }
}

// ---------------------------------------------------------------------------
// Workspace layout (44,978,176 B; scratch only touched on topk overflow):
//   0        qT 2MB [gemm->k345]
//   2097152  kT 2MB | 4194304 vT 2MB | 6291456 (avT region unused now)
//   8388608  xx 16KB | 8404992 idxb 320KB | 8732672 stats 2KB | 8734720 b1p 2KB
//   8736768  wq/wk/wv frags 6x32KB
//   8933376  wcFhi/lo 2x128KB | 9195520 w2Fhi/lo 2x64KB
//   9326592  xhiF 1MB | 10375168 xloF 1MB
//   11423744 scratch 32MB (topk overflow fallback only)
// ---------------------------------------------------------------------------
#define WS_FULL 44978176u

extern "C" void kernel_launch(void* const* d_in, const int* in_sizes, int n_in,
                              void* d_out, int out_size, void* d_ws, size_t ws_size,
                              hipStream_t stream) {
    fp desc1 = (fp)d_in[0];
    fp wq = (fp)d_in[1];  fp bq = (fp)d_in[2];
    fp wk = (fp)d_in[3];  fp bk = (fp)d_in[4];
    fp wv = (fp)d_in[5];  fp bv = (fp)d_in[6];
    fp wm = (fp)d_in[7];  fp bm = (fp)d_in[8];
    fp w1 = (fp)d_in[9];  fp b1 = (fp)d_in[10];
    fp gamma = (fp)d_in[11]; fp beta = (fp)d_in[12];
    fp w2 = (fp)d_in[13]; fp b2 = (fp)d_in[14];

    if (ws_size < (size_t)WS_FULL) return;  // all-zero out => ws too small

    char* ws = (char*)d_ws;
    float*  qT    = (float*) (ws + 0);
    float*  kT    = (float*) (ws + 2097152);
    float*  vT    = (float*) (ws + 4194304);
    float*  xx    = (float*) (ws + 8388608);
    int*    idxb  = (int*)   (ws + 8404992);
    float*  stats = (float*) (ws + 8732672);
    float*  b1p   = (float*) (ws + 8734720);
    ushort* wqFhi = (ushort*)(ws + 8736768);
    ushort* wqFlo = (ushort*)(ws + 8769536);
    ushort* wkFhi = (ushort*)(ws + 8802304);
    ushort* wkFlo = (ushort*)(ws + 8835072);
    ushort* wvFhi = (ushort*)(ws + 8867840);
    ushort* wvFlo = (ushort*)(ws + 8900608);
    ushort* wcFhi = (ushort*)(ws + 8933376);
    ushort* wcFlo = (ushort*)(ws + 9064448);
    ushort* w2Fhi = (ushort*)(ws + 9195520);
    ushort* w2Flo = (ushort*)(ws + 9261056);
    ushort* xhiF  = (ushort*)(ws + 9326592);
    ushort* xloF  = (ushort*)(ws + 10375168);
    float*  scratch = (float*)(ws + 11423744);
    float*  outp  = (float*)d_out;

    prep_all<<<835, 256, 0, stream>>>(desc1, wq, wk, wv, wm, w1, w2, bm, b1,
                                      xx, xhiF, xloF,
                                      wqFhi, wqFlo, wkFhi, wkFlo, wvFhi, wvFlo,
                                      wcFhi, wcFlo, w2Fhi, w2Flo, b1p, stats);
    gemm_key_topk<<<256, 1024, 0, stream>>>(xhiF, xloF, xx,
                                            wqFhi, wqFlo, wkFhi, wkFlo,
                                            wvFhi, wvFlo,
                                            bq, bk, bv, qT, kT, vT,
                                            idxb, scratch);
    {
        fp qTc = qT, kTc = kT, vTc = vT;
        const int* idxc = idxb;
        const ushort* xhiFc = xhiF; const ushort* xloFc = xloF;
        const ushort* wcFhic = wcFhi; const ushort* wcFloc = wcFlo;
        const float* b1pc = b1p;
        const ushort* w2Fhic = w2Fhi; const ushort* w2Floc = w2Flo;
        void* args[] = { &qTc, &kTc, &vTc, &idxc, &xhiFc, &xloFc,
                         &wcFhic, &wcFloc, &b1pc, &stats,
                         &gamma, &beta, &w2Fhic, &w2Floc,
                         &b2, &desc1, &outp };
        hipLaunchCooperativeKernel((const void*)k345_fused,
                                   dim3(256), dim3(1024), args, 0, stream);
    }
}

// Round 11
// 205.947 us; speedup vs baseline: 1.0088x; 1.0088x over previous
//
#include <hip/hip_runtime.h>
#include <hip/hip_cooperative_groups.h>
#include <math.h>

namespace cg = cooperative_groups;

#define NPT 2048
#define KNN 20

typedef const float* fp;
typedef __attribute__((ext_vector_type(4))) float f32x4;
typedef __attribute__((ext_vector_type(8))) short s16x8;

// round-to-nearest-even f32 -> bf16 bits (inputs are finite)
__device__ __forceinline__ ushort f2bf_rne(float v) {
    unsigned u = __float_as_uint(v);
    unsigned r = u + 0x7FFFu + ((u >> 16) & 1u);
    return (ushort)(r >> 16);
}
__device__ __forceinline__ float bfbits2f(ushort h) {
    return __uint_as_float(((unsigned)h) << 16);
}
__device__ __forceinline__ s16x8 ldfrag(const ushort* p) {
    union { uint4 u; s16x8 s; } cv;
    cv.u = *reinterpret_cast<const uint4*>(p);
    return cv.s;
}
// 8 consecutive f32 -> bf16 hi/lo fragment pair (in-register fragify)
__device__ __forceinline__ void f8_hilo(const float* row, s16x8* hi, s16x8* lo) {
    float4 f0 = *reinterpret_cast<const float4*>(row);
    float4 f1 = *reinterpret_cast<const float4*>(row + 4);
    float f[8] = {f0.x, f0.y, f0.z, f0.w, f1.x, f1.y, f1.z, f1.w};
    union { ushort u[8]; s16x8 s; } H, L;
    #pragma unroll
    for (int j = 0; j < 8; j++) {
        ushort h = f2bf_rne(f[j]);
        H.u[j] = h;
        L.u[j] = f2bf_rne(f[j] - bfbits2f(h));
    }
    *hi = H.s; *lo = L.s;
}

// ---------------------------------------------------------------------------
// prep_all: blocks [0,256) = fragify x + xx; blocks [256,835) = weight frags
//   (q/k/v K=128; wc=[w1x | w1a@wm] K=256 on-the-fly; w2 K=256), b1p, stats=0.
// ---------------------------------------------------------------------------
__global__ __launch_bounds__(256) void prep_all(
    fp xbf, fp wq, fp wk, fp wv, fp wm, fp w1, fp w2, fp bm, fp b1,
    float* xx, ushort* xhiF, ushort* xloF,
    ushort* wqFhi, ushort* wqFlo, ushort* wkFhi, ushort* wkFlo,
    ushort* wvFhi, ushort* wvFlo,
    ushort* wcFhi, ushort* wcFlo, ushort* w2Fhi, ushort* w2Flo,
    float* b1p, float* stats) {
    int t = threadIdx.x;
    if (blockIdx.x < 256) {                 // ---- x frags + xx ----
        __shared__ float xs[16][129];
        __shared__ float xpart[16][17];
        int p0 = blockIdx.x * 16;
        int b = p0 >> 11, n0 = p0 & 2047;
        fp xb = xbf + (size_t)b * 128 * NPT;
        {
            int c = t >> 1, half = t & 1;
            float4 f0 = *reinterpret_cast<const float4*>(xb + (size_t)c * NPT + n0 + half * 8);
            float4 f1 = *reinterpret_cast<const float4*>(xb + (size_t)c * NPT + n0 + half * 8 + 4);
            xs[half * 8 + 0][c] = f0.x; xs[half * 8 + 1][c] = f0.y;
            xs[half * 8 + 2][c] = f0.z; xs[half * 8 + 3][c] = f0.w;
            xs[half * 8 + 4][c] = f1.x; xs[half * 8 + 5][c] = f1.y;
            xs[half * 8 + 6][c] = f1.z; xs[half * 8 + 7][c] = f1.w;
        }
        __syncthreads();
        int p = t & 15, g = t >> 4, c0 = g * 8;
        float f[8];
        #pragma unroll
        for (int j = 0; j < 8; j++) f[j] = xs[p][c0 + j];
        float ps = 0.f;
        #pragma unroll
        for (int j = 0; j < 8; j++) ps += f[j] * f[j];
        xpart[p][g] = ps;
        union { ushort u[8]; uint4 q; } H, L;
        #pragma unroll
        for (int j = 0; j < 8; j++) {
            ushort hi = f2bf_rne(f[j]);
            H.u[j] = hi;
            L.u[j] = f2bf_rne(f[j] - bfbits2f(hi));
        }
        size_t off = ((size_t)blockIdx.x * 4 + (c0 >> 5)) * 512
                   + (size_t)(((((c0 >> 3) & 3) * 16) + p) * 8);
        *reinterpret_cast<uint4*>(xhiF + off) = H.q;
        *reinterpret_cast<uint4*>(xloF + off) = L.q;
        __syncthreads();
        if (t < 16) {
            float s = 0.f;
            #pragma unroll
            for (int gg = 0; gg < 16; gg++) s += xpart[t][gg];
            xx[p0 + t] = s;
        }
        return;
    }
    int wid = (blockIdx.x - 256) * 256 + t;
    if (wid < 49152) {                      // q/k/v frags (K=128)
        int which = wid >> 14, e = wid & 16383;
        int lane = (e >> 3) & 63, j = e & 7, kk = (e >> 9) & 3, nt = e >> 11;
        int n = nt * 16 + (lane & 15);
        int k = kk * 32 + (lane >> 4) * 8 + j;
        fp src = which == 0 ? wq : which == 1 ? wk : wv;
        float v = src[n * 128 + k];
        ushort hi = f2bf_rne(v);
        (which == 0 ? wqFhi : which == 1 ? wkFhi : wvFhi)[e] = hi;
        (which == 0 ? wqFlo : which == 1 ? wkFlo : wvFlo)[e] = f2bf_rne(v - bfbits2f(hi));
    } else if (wid < 114688) {              // wc frags (N=256, K=256)
        int e = wid - 49152;
        int j = e & 7, lane = (e >> 3) & 63, kk = (e >> 9) & 7, nt = e >> 12;
        int n = nt * 16 + (lane & 15);
        int k = kk * 32 + (lane >> 4) * 8 + j;
        float v;
        if (k < 128) {
            v = w1[n * 256 + k];
        } else {                            // W[n][k-128] = w1a@wm on the fly
            int c = k - 128;
            float s = 0.f;
            for (int i = 0; i < 128; i += 4) {
                float4 wr = *reinterpret_cast<const float4*>(w1 + n * 256 + 128 + i);
                s += wr.x * wm[(i + 0) * 128 + c];
                s += wr.y * wm[(i + 1) * 128 + c];
                s += wr.z * wm[(i + 2) * 128 + c];
                s += wr.w * wm[(i + 3) * 128 + c];
            }
            v = s;
        }
        ushort hi = f2bf_rne(v);
        wcFhi[e] = hi;
        wcFlo[e] = f2bf_rne(v - bfbits2f(hi));
    } else if (wid < 147456) {              // w2 frags (N=128, K=256)
        int e = wid - 114688;
        int j = e & 7, lane = (e >> 3) & 63, kk = (e >> 9) & 7, nt = e >> 12;
        int n = nt * 16 + (lane & 15);
        int k = kk * 32 + (lane >> 4) * 8 + j;
        float v = w2[n * 256 + k];
        ushort hi = f2bf_rne(v);
        w2Fhi[e] = hi;
        w2Flo[e] = f2bf_rne(v - bfbits2f(hi));
    } else if (wid < 147712) {              // b1p = b1 + w1a@bm
        int o = wid - 147456;
        float s = b1[o];
        for (int i = 0; i < 128; i++)
            s += w1[o * 256 + 128 + i] * bm[i];
        b1p[o] = s;
    } else {                                // BN stats zero (512)
        stats[wid - 147712] = 0.0f;
    }
}

// ---------------------------------------------------------------------------
// gemm_key_topk v8: qkv + key GEMM + exact in-kernel top-20 (unchanged r9).
// ---------------------------------------------------------------------------
#define MERGE(off) { float ov = __shfl_xor(bv, off); int oi = __shfl_xor(bi, off); \
                     if (ov > bv || (ov == bv && oi < bi)) { bv = ov; bi = oi; } }

#define KEYPAIR(C0, D0, D1) { \
    int ct0 = slab * 128 + w * 8 + C0; \
    int ct1 = ct0 + 1; \
    f32x4 a0 = (f32x4){0.f, 0.f, 0.f, 0.f}; \
    f32x4 a1 = (f32x4){0.f, 0.f, 0.f, 0.f}; \
    _Pragma("unroll 2") \
    for (int kk = 0; kk < 4; kk++) { \
        s16x8 ah = ldfrag(Ahi[kk] + lane * 8); \
        s16x8 al = ldfrag(Alo[kk] + lane * 8); \
        s16x8 b0h = ldfrag(xhiF + ((size_t)(ct0 * 4 + kk)) * 512 + lane * 8); \
        s16x8 b0l = ldfrag(xloF + ((size_t)(ct0 * 4 + kk)) * 512 + lane * 8); \
        s16x8 b1h = ldfrag(xhiF + ((size_t)(ct1 * 4 + kk)) * 512 + lane * 8); \
        s16x8 b1l = ldfrag(xloF + ((size_t)(ct1 * 4 + kk)) * 512 + lane * 8); \
        a0 = __builtin_amdgcn_mfma_f32_16x16x32_bf16(ah, b0h, a0, 0, 0, 0); \
        a1 = __builtin_amdgcn_mfma_f32_16x16x32_bf16(ah, b1h, a1, 0, 0, 0); \
        a0 = __builtin_amdgcn_mfma_f32_16x16x32_bf16(al, b0h, a0, 0, 0, 0); \
        a1 = __builtin_amdgcn_mfma_f32_16x16x32_bf16(al, b1h, a1, 0, 0, 0); \
        a0 = __builtin_amdgcn_mfma_f32_16x16x32_bf16(ah, b0l, a0, 0, 0, 0); \
        a1 = __builtin_amdgcn_mfma_f32_16x16x32_bf16(ah, b1l, a1, 0, 0, 0); \
    } \
    float xx0 = xx[slab * 2048 + (w * 8 + C0) * 16 + cl]; \
    float xx1 = xx[slab * 2048 + (w * 8 + C0 + 1) * 16 + cl]; \
    a0[0] = 2.0f * a0[0] - xx0; a0[1] = 2.0f * a0[1] - xx0; \
    a0[2] = 2.0f * a0[2] - xx0; a0[3] = 2.0f * a0[3] - xx0; \
    a1[0] = 2.0f * a1[0] - xx1; a1[1] = 2.0f * a1[1] - xx1; \
    a1[2] = 2.0f * a1[2] - xx1; a1[3] = 2.0f * a1[3] - xx1; \
    D0 = a0; D1 = a1; \
}

__global__ __launch_bounds__(1024, 4) void gemm_key_topk(
    const ushort* xhiF, const ushort* xloF, const float* xx,
    const ushort* wqFhi, const ushort* wqFlo,
    const ushort* wkFhi, const ushort* wkFlo,
    const ushort* wvFhi, const ushort* wvFlo,
    fp bq, fp bk, fp bv_, float* qT, float* kT, float* vT,
    int* idxbuf, float* scratch) {
    __shared__ ushort Ahi[4][512];          // 4 KB  A-frags hi [kk][lane*8]
    __shared__ ushort Alo[4][512];          // 4 KB  A-frags lo
    __shared__ float chm[16][64];           // 4 KB  per-row chunk maxima
    __shared__ float sv[16][256];           // 16 KB survivor values
    __shared__ int   si[16][256];           // 16 KB survivor cols
    __shared__ float Trow[16];
    __shared__ int   rowcnt[16];
    __shared__ int   ovfAll;
    int tt = threadIdx.x, w = tt >> 6, lane = tt & 63;
    int rt = blockIdx.x;                    // row-tile 0..255
    int slab = rt >> 7, rtl = rt & 127;
    int cl = lane & 15, quad = lane >> 4;

    if (tt < 16) rowcnt[tt] = 0;

    // ---- stage A-frags to LDS (512 threads x 16B = 8 KB) ----
    if (tt < 512) {
        int which = tt >> 8, kk = (tt >> 6) & 3, ln = tt & 63;
        const ushort* src = (which ? xloF : xhiF)
                          + ((size_t)(rt * 4 + kk)) * 512 + ln * 8;
        uint4 v = *reinterpret_cast<const uint4*>(src);
        *reinterpret_cast<uint4*>((which ? Alo[kk] : Ahi[kk]) + ln * 8) = v;
    }
    __syncthreads();

    // ---- Phase 1: qkv (24 (mat,nt) pairs; waves 0..11 take 2 each) ----
    if (w < 12) {
        f32x4 acc0 = (f32x4){0.f, 0.f, 0.f, 0.f};
        f32x4 acc1 = (f32x4){0.f, 0.f, 0.f, 0.f};
        int pair0 = w * 2, pair1 = w * 2 + 1;
        int mat0 = pair0 >> 3, nt0 = pair0 & 7;
        int mat1 = pair1 >> 3, nt1 = pair1 & 7;
        const ushort* w0hi = mat0 == 0 ? wqFhi : mat0 == 1 ? wkFhi : wvFhi;
        const ushort* w0lo = mat0 == 0 ? wqFlo : mat0 == 1 ? wkFlo : wvFlo;
        const ushort* w1hi = mat1 == 0 ? wqFhi : mat1 == 1 ? wkFhi : wvFhi;
        const ushort* w1lo = mat1 == 0 ? wqFlo : mat1 == 1 ? wkFlo : wvFlo;
        #pragma unroll 2
        for (int kk = 0; kk < 4; kk++) {
            s16x8 ah = ldfrag(Ahi[kk] + lane * 8);
            s16x8 al = ldfrag(Alo[kk] + lane * 8);
            s16x8 b0h = ldfrag(w0hi + ((size_t)(nt0 * 4 + kk)) * 512 + lane * 8);
            s16x8 b0l = ldfrag(w0lo + ((size_t)(nt0 * 4 + kk)) * 512 + lane * 8);
            s16x8 b1h = ldfrag(w1hi + ((size_t)(nt1 * 4 + kk)) * 512 + lane * 8);
            s16x8 b1l = ldfrag(w1lo + ((size_t)(nt1 * 4 + kk)) * 512 + lane * 8);
            acc0 = __builtin_amdgcn_mfma_f32_16x16x32_bf16(ah, b0h, acc0, 0, 0, 0);
            acc1 = __builtin_amdgcn_mfma_f32_16x16x32_bf16(ah, b1h, acc1, 0, 0, 0);
            acc0 = __builtin_amdgcn_mfma_f32_16x16x32_bf16(al, b0h, acc0, 0, 0, 0);
            acc1 = __builtin_amdgcn_mfma_f32_16x16x32_bf16(al, b1h, acc1, 0, 0, 0);
            acc0 = __builtin_amdgcn_mfma_f32_16x16x32_bf16(ah, b0l, acc0, 0, 0, 0);
            acc1 = __builtin_amdgcn_mfma_f32_16x16x32_bf16(ah, b1l, acc1, 0, 0, 0);
        }
        int p0 = rt * 16;
        {
            fp bias    = mat0 == 0 ? bq : mat0 == 1 ? bk : bv_;
            float* out = mat0 == 0 ? qT : mat0 == 1 ? kT : vT;
            int o = nt0 * 16 + cl;
            float bvv = bias[o];
            #pragma unroll
            for (int r = 0; r < 4; r++)
                out[(size_t)(p0 + quad * 4 + r) * 128 + o] = acc0[r] + bvv;
        }
        {
            fp bias    = mat1 == 0 ? bq : mat1 == 1 ? bk : bv_;
            float* out = mat1 == 0 ? qT : mat1 == 1 ? kT : vT;
            int o = nt1 * 16 + cl;
            float bvv = bias[o];
            #pragma unroll
            for (int r = 0; r < 4; r++)
                out[(size_t)(p0 + quad * 4 + r) * 128 + o] = acc1[r] + bvv;
        }
    }
    __builtin_amdgcn_sched_barrier(0);

    // ---- Phase 2: key GEMM, 8 named regs, 4 ILP-pairs ----
    f32x4 key0, key1, key2, key3, key4, key5, key6, key7;
    KEYPAIR(0, key0, key1)
    __builtin_amdgcn_sched_barrier(0);
    KEYPAIR(2, key2, key3)
    __builtin_amdgcn_sched_barrier(0);
    KEYPAIR(4, key4, key5)
    __builtin_amdgcn_sched_barrier(0);
    KEYPAIR(6, key6, key7)
    __builtin_amdgcn_sched_barrier(0);

    // ---- chunk maxima: chunks of 32 cols (8 c-tiles x 4 cl); 64/row ----
    {
        float m[4];
        #pragma unroll
        for (int r = 0; r < 4; r++) {
            float mm = fmaxf(fmaxf(fmaxf(key0[r], key1[r]), fmaxf(key2[r], key3[r])),
                             fmaxf(fmaxf(key4[r], key5[r]), fmaxf(key6[r], key7[r])));
            mm = fmaxf(mm, __shfl_xor(mm, 1));
            mm = fmaxf(mm, __shfl_xor(mm, 2));
            m[r] = mm;
        }
        if ((cl & 3) == 0) {
            #pragma unroll
            for (int r = 0; r < 4; r++)
                chm[quad * 4 + r][w * 4 + (cl >> 2)] = m[r];
        }
    }
    __syncthreads();

    // ---- per-row threshold: wave w sorts row w's 64 chunk maxima ----
    {
        float bs = chm[w][lane];
        #pragma unroll
        for (int k = 2; k <= 64; k <<= 1) {
            #pragma unroll
            for (int j = k >> 1; j > 0; j >>= 1) {
                float o = __shfl_xor(bs, j);
                bool dirDesc = (lane & k) != 0;
                bool upper   = (lane & j) != 0;
                bs = (upper != dirDesc) ? fmaxf(bs, o) : fminf(bs, o);
            }
        }
        float T = __shfl(bs, 44);           // 20th largest chunk max <= v20
        if (lane == 0) Trow[w] = T;
    }
    __syncthreads();

    // ---- survivor compaction (atomic append per row) ----
    #pragma unroll
    for (int r = 0; r < 4; r++) {
        int row = quad * 4 + r;
        float T = Trow[row];
        float vals[8] = {key0[r], key1[r], key2[r], key3[r],
                         key4[r], key5[r], key6[r], key7[r]};
        #pragma unroll
        for (int c = 0; c < 8; c++) {
            float v = vals[c];
            if (v >= T) {
                int pos = atomicAdd(&rowcnt[row], 1);
                if (pos < 256) {
                    sv[row][pos] = v;
                    si[row][pos] = (w * 8 + c) * 16 + cl;
                }
            }
        }
    }
    __syncthreads();
    if (tt == 0) {
        int o = 0;
        for (int i = 0; i < 16; i++) o |= (rowcnt[i] > 256) ? 1 : 0;
        ovfAll = o;
    }
    __syncthreads();
    int ovf = ovfAll;

    // ---- in-kernel final selection: wave w owns row w ----
    int S = rowcnt[w];
    int rowg = slab * 2048 + rtl * 16 + w;
    if (S <= 64) {                          // common case (S>=20 guaranteed)
        float v; int idx;
        if (lane < S) { v = sv[w][lane]; idx = si[w][lane]; }
        else          { v = -3.4e38f;    idx = 0x7FFFFFFF; }
        #pragma unroll
        for (int k = 2; k <= 64; k <<= 1) {
            #pragma unroll
            for (int j = k >> 1; j > 0; j >>= 1) {
                float ov = __shfl_xor(v, j); int oi = __shfl_xor(idx, j);
                bool dirDesc = (lane & k) != 0;
                bool upper   = (lane & j) != 0;
                bool takeMax = (upper != dirDesc);
                bool amax = (v > ov) || (v == ov && idx < oi);
                if (takeMax != amax) { v = ov; idx = oi; }
            }
        }
        if (lane >= 44) idxbuf[(size_t)rowg * KNN + (63 - lane)] = idx;
    } else if (S <= 256) {                  // exact iterative extract
        float vl[4]; int il[4];
        #pragma unroll
        for (int s = 0; s < 4; s++) {
            int g = lane + s * 64;
            bool ok = g < S;
            vl[s] = ok ? sv[w][g] : -3.4e38f;
            il[s] = ok ? si[w][g] : 0x7FFFFFFF;
        }
        unsigned removed = 0u;
        for (int iter = 0; iter < KNN; iter++) {
            float bv = -3.4e38f; int bi = 0x7FFFFFFF;
            #pragma unroll
            for (int s = 0; s < 4; s++) {
                bool live = ((removed >> s) & 1u) == 0u;
                if (live && (vl[s] > bv || (vl[s] == bv && il[s] < bi))) {
                    bv = vl[s]; bi = il[s];
                }
            }
            MERGE(32) MERGE(16) MERGE(8) MERGE(4) MERGE(2) MERGE(1)
            if (lane == 0) idxbuf[(size_t)rowg * KNN + iter] = bi;
            #pragma unroll
            for (int s = 0; s < 4; s++)     // indices unique: safe removal
                if (il[s] == bi) removed |= 1u << s;
        }
    }

    // ---- exact overflow fallback (never expected; correctness only) ----
    if (ovf) {
        #pragma unroll
        for (int r = 0; r < 4; r++) {
            float vals[8] = {key0[r], key1[r], key2[r], key3[r],
                             key4[r], key5[r], key6[r], key7[r]};
            #pragma unroll
            for (int c = 0; c < 8; c++)
                scratch[((size_t)rt * 16 + quad * 4 + r) * 2048
                        + (w * 8 + c) * 16 + cl] = vals[c];
        }
        __syncthreads();
        if (rowcnt[w] > 256) {
            const float* rowp = scratch + ((size_t)rt * 16 + w) * 2048;
            float rv[32];
            #pragma unroll
            for (int j = 0; j < 32; j++) rv[j] = rowp[j * 64 + lane];
            unsigned removed = 0u;
            for (int iter = 0; iter < KNN; iter++) {
                float bv = -3.4e38f; int bi = 0;
                #pragma unroll
                for (int sl = 0; sl < 32; sl++) {
                    bool live = ((removed >> sl) & 1u) == 0u;
                    if (live && rv[sl] > bv) { bv = rv[sl]; bi = sl * 64 + lane; }
                }
                MERGE(32) MERGE(16) MERGE(8) MERGE(4) MERGE(2) MERGE(1)
                if (lane == 0) idxbuf[(size_t)rowg * KNN + iter] = bi;
                if ((bi & 63) == lane) removed |= 1u << (bi >> 6);
            }
        }
    }
}

// ---------------------------------------------------------------------------
// k3 v2 (round-9 version, standalone): sparse mutual-KNN attention,
//   2 points/block, 2048 blocks — full occupancy for the gather phase.
// ---------------------------------------------------------------------------
__global__ __launch_bounds__(256) void k3_attn(
    fp qT, fp kT, fp vT, const int* idxbuf, float* avT) {
    __shared__ float sbuf[2][KNN * 4];
    __shared__ int   mlist[2][KNN];
    __shared__ int   cnt_s[2];
    int tt = threadIdx.x;
    int half = tt >> 7, t = tt & 127;
    int p = blockIdx.x * 2 + half;
    int b = p >> 11, n = p & 2047;
    int bbase = b * NPT;
    int h = t >> 5;

    if ((tt >> 6) == half * 2) {
        int lane = tt & 63;
        bool fl = false; int m = 0;
        if (lane < KNN) {
            m = idxbuf[(size_t)p * KNN + lane] & 2047;
            const int4* mrow = reinterpret_cast<const int4*>(idxbuf + (size_t)(bbase + m) * KNN);
            int4 r0 = mrow[0], r1 = mrow[1], r2 = mrow[2], r3 = mrow[3], r4 = mrow[4];
            fl = (r0.x == n) || (r0.y == n) || (r0.z == n) || (r0.w == n)
              || (r1.x == n) || (r1.y == n) || (r1.z == n) || (r1.w == n)
              || (r2.x == n) || (r2.y == n) || (r2.z == n) || (r2.w == n)
              || (r3.x == n) || (r3.y == n) || (r3.z == n) || (r3.w == n)
              || (r4.x == n) || (r4.y == n) || (r4.z == n) || (r4.w == n);
        }
        unsigned long long mask = __ballot(fl);
        int pos = __popcll(mask & ((1ull << lane) - 1ull));
        if (fl) mlist[half][pos] = m;
        if (lane == 0) cnt_s[half] = (int)__popcll(mask);
    }
    __syncthreads();

    int cnt = cnt_s[half];
    float qv = qT[(size_t)p * 128 + t];
    int jj = 0;
    for (; jj + 1 < cnt; jj += 2) {
        int m0 = mlist[half][jj], m1 = mlist[half][jj + 1];
        float pr0 = qv * kT[(size_t)(bbase + m0) * 128 + t];
        float pr1 = qv * kT[(size_t)(bbase + m1) * 128 + t];
        pr0 += __shfl_xor(pr0, 16); pr1 += __shfl_xor(pr1, 16);
        pr0 += __shfl_xor(pr0, 8);  pr1 += __shfl_xor(pr1, 8);
        pr0 += __shfl_xor(pr0, 4);  pr1 += __shfl_xor(pr1, 4);
        pr0 += __shfl_xor(pr0, 2);  pr1 += __shfl_xor(pr1, 2);
        pr0 += __shfl_xor(pr0, 1);  pr1 += __shfl_xor(pr1, 1);
        if ((t & 31) == 0) {
            sbuf[half][jj * 4 + h]       = pr0 * 0.17677669529663687f;
            sbuf[half][(jj + 1) * 4 + h] = pr1 * 0.17677669529663687f;
        }
    }
    if (jj < cnt) {
        int m = mlist[half][jj];
        float prod = qv * kT[(size_t)(bbase + m) * 128 + t];
        prod += __shfl_xor(prod, 16);
        prod += __shfl_xor(prod, 8);
        prod += __shfl_xor(prod, 4);
        prod += __shfl_xor(prod, 2);
        prod += __shfl_xor(prod, 1);
        if ((t & 31) == 0) sbuf[half][jj * 4 + h] = prod * 0.17677669529663687f;
    }
    __syncthreads();

    float mx = -3.4e38f;
    for (int j = 0; j < cnt; j++) mx = fmaxf(mx, sbuf[half][j * 4 + h]);
    float den = 0.f, accv = 0.f;
    for (int j = 0; j < cnt; j++) {
        float ex = expf(sbuf[half][j * 4 + h] - mx);
        den += ex;
        accv += ex * vT[(size_t)(bbase + mlist[half][j]) * 128 + t];
    }
    float inv = (cnt > 0) ? (1.0f / den) : 0.0f;
    avT[(size_t)p * 128 + t] = accv * inv;
}

// ---------------------------------------------------------------------------
// k45_fused: cooperative, 256 blocks x 1024 threads — NO occupancy loss vs
//   the split pair (k4b was 16 waves/CU; k5b phase uses waves 0-7 = same 8).
//   Phase A (k4b v2): stage x-frags + fragify avT once; wave w computes
//     nt=w; h rows stay in LDS (Hb, padded rows); BN stats global atomics.
//   grid.sync()  — replaces the kernel boundary (the only global dep).
//   Phase B (k5b v2): BN+relu+fragify from Hb (waves 0-7, kk=w); wave w
//     computes nt=w; out = w2@relu(BN(h)) + b2 + x.
//   Identical math/MFMA order -> bit-identical output. Saves one launch
//   boundary + the 8 MB hbuf HBM round-trip.
// ---------------------------------------------------------------------------
__global__ __launch_bounds__(1024) void k45_fused(
    const ushort* xhiF, const ushort* xloF, const float* avT,
    const ushort* wcFhi, const ushort* wcFlo,
    const float* b1p, float* stats,
    fp gamma, fp beta,
    const ushort* w2Fhi, const ushort* w2Flo,
    fp b2, fp xbf, float* out) {
    __shared__ ushort AH[8][512];           // 8 KB; reused as HH in phase B
    __shared__ ushort AL[8][512];           // 8 KB; reused as HL in phase B
    __shared__ float Hb[16][260];           // 16.6 KB (padded rows)
    int tt = threadIdx.x, w = tt >> 6, lane = tt & 63;
    int rt = blockIdx.x;                    // 0..255
    int p0 = rt * 16;
    int cl = lane & 15, quad = lane >> 4;

    // ---- Phase A staging (x part: copy; av part: fragify once) ----
    if (w < 8) {
        int which = w & 1, kk = w >> 1;
        const ushort* src = (which ? xloF : xhiF)
                          + ((size_t)(rt * 4 + kk)) * 512 + lane * 8;
        uint4 v = *reinterpret_cast<const uint4*>(src);
        *reinterpret_cast<uint4*>((which ? AL[kk] : AH[kk]) + lane * 8) = v;
    } else if (w < 12) {
        int kk = 4 + (w - 8);
        const float* arow = avT + (size_t)(p0 + (lane & 15)) * 128
                          + (kk - 4) * 32 + (lane >> 4) * 8;
        s16x8 hi, lo;
        f8_hilo(arow, &hi, &lo);
        union { s16x8 s; uint4 u; } cvh, cvl;
        cvh.s = hi; cvl.s = lo;
        *reinterpret_cast<uint4*>(AH[kk] + lane * 8) = cvh.u;
        *reinterpret_cast<uint4*>(AL[kk] + lane * 8) = cvl.u;
    }
    __syncthreads();

    // ---- Phase A compute: wave w owns nt = w (16 waves) ----
    {
        int nt = w;
        f32x4 acc = (f32x4){0.f, 0.f, 0.f, 0.f};
        for (int kk = 0; kk < 8; kk++) {
            s16x8 ahi = ldfrag(AH[kk] + lane * 8);
            s16x8 alo = ldfrag(AL[kk] + lane * 8);
            s16x8 bhi = ldfrag(wcFhi + ((size_t)(nt * 8 + kk)) * 512 + lane * 8);
            s16x8 blo = ldfrag(wcFlo + ((size_t)(nt * 8 + kk)) * 512 + lane * 8);
            acc = __builtin_amdgcn_mfma_f32_16x16x32_bf16(ahi, bhi, acc, 0, 0, 0);
            acc = __builtin_amdgcn_mfma_f32_16x16x32_bf16(alo, bhi, acc, 0, 0, 0);
            acc = __builtin_amdgcn_mfma_f32_16x16x32_bf16(ahi, blo, acc, 0, 0, 0);
        }
        int o = nt * 16 + cl;
        float bb = b1p[o];
        float s = 0.f, s2 = 0.f;
        #pragma unroll
        for (int r = 0; r < 4; r++) {
            float v = acc[r] + bb;
            Hb[quad * 4 + r][o] = v;
            s += v; s2 += v * v;
        }
        s  += __shfl_xor(s, 16);  s  += __shfl_xor(s, 32);
        s2 += __shfl_xor(s2, 16); s2 += __shfl_xor(s2, 32);
        if (quad == 0) {
            atomicAdd(&stats[o], s);
            atomicAdd(&stats[256 + o], s2);
        }
    }

    cg::this_grid().sync();                 // BN stats complete device-wide

    // ---- Phase B staging: wave w converts kk=w (BN + relu + fragify) ----
    if (w < 8) {
        int kk = w;
        int c0 = kk * 32 + (lane >> 4) * 8;
        const float* hrow = &Hb[lane & 15][c0];
        float4 f0 = *reinterpret_cast<const float4*>(hrow);
        float4 f1 = *reinterpret_cast<const float4*>(hrow + 4);
        float4 s0 = *reinterpret_cast<const float4*>(stats + c0);
        float4 s1 = *reinterpret_cast<const float4*>(stats + c0 + 4);
        float4 q0 = *reinterpret_cast<const float4*>(stats + 256 + c0);
        float4 q1 = *reinterpret_cast<const float4*>(stats + 256 + c0 + 4);
        float4 g0 = *reinterpret_cast<const float4*>(gamma + c0);
        float4 g1 = *reinterpret_cast<const float4*>(gamma + c0 + 4);
        float4 e0 = *reinterpret_cast<const float4*>(beta + c0);
        float4 e1 = *reinterpret_cast<const float4*>(beta + c0 + 4);
        float f[8] = {f0.x, f0.y, f0.z, f0.w, f1.x, f1.y, f1.z, f1.w};
        float sm[8] = {s0.x, s0.y, s0.z, s0.w, s1.x, s1.y, s1.z, s1.w};
        float sq[8] = {q0.x, q0.y, q0.z, q0.w, q1.x, q1.y, q1.z, q1.w};
        float gm[8] = {g0.x, g0.y, g0.z, g0.w, g1.x, g1.y, g1.z, g1.w};
        float bt[8] = {e0.x, e0.y, e0.z, e0.w, e1.x, e1.y, e1.z, e1.w};
        union { ushort u[8]; uint4 q; } H, L;
        #pragma unroll
        for (int j = 0; j < 8; j++) {
            float mu  = sm[j] * (1.0f / 4096.0f);
            float var = fmaxf(sq[j] * (1.0f / 4096.0f) - mu * mu, 0.0f);
            float a    = gm[j] / sqrtf(var + 1e-5f);
            float cadd = bt[j] - mu * a;
            float v = fmaxf(f[j] * a + cadd, 0.0f);
            ushort hi = f2bf_rne(v);
            H.u[j] = hi;
            L.u[j] = f2bf_rne(v - bfbits2f(hi));
        }
        *reinterpret_cast<uint4*>(AH[kk] + lane * 8) = H.q;   // HH
        *reinterpret_cast<uint4*>(AL[kk] + lane * 8) = L.q;   // HL
    }
    __syncthreads();

    // ---- Phase B compute: wave w owns nt = w (waves 0-7) ----
    if (w < 8) {
        int nt = w;
        f32x4 acc = (f32x4){0.f, 0.f, 0.f, 0.f};
        for (int kk = 0; kk < 8; kk++) {
            s16x8 ahi = ldfrag(AH[kk] + lane * 8);
            s16x8 alo = ldfrag(AL[kk] + lane * 8);
            s16x8 bhi = ldfrag(w2Fhi + ((size_t)(nt * 8 + kk)) * 512 + lane * 8);
            s16x8 blo = ldfrag(w2Flo + ((size_t)(nt * 8 + kk)) * 512 + lane * 8);
            acc = __builtin_amdgcn_mfma_f32_16x16x32_bf16(ahi, bhi, acc, 0, 0, 0);
            acc = __builtin_amdgcn_mfma_f32_16x16x32_bf16(alo, bhi, acc, 0, 0, 0);
            acc = __builtin_amdgcn_mfma_f32_16x16x32_bf16(ahi, blo, acc, 0, 0, 0);
        }
        int b = p0 >> 11, n0 = p0 & 2047;
        int o = nt * 16 + cl;
        float bb = b2[o];
        size_t base = (size_t)b * 128 * NPT + (size_t)o * NPT + n0 + quad * 4;
        float4 xv = *reinterpret_cast<const float4*>(xbf + base);
        float4 ov;
        ov.x = acc[0] + bb + xv.x;
        ov.y = acc[1] + bb + xv.y;
        ov.z = acc[2] + bb + xv.z;
        ov.w = acc[3] + bb + xv.w;
        *reinterpret_cast<float4*>(out + base) = ov;
    }
}

// ---------------------------------------------------------------------------
// Workspace layout (44,978,176 B; scratch only touched on topk overflow):
//   0        qT 2MB [gemm->k3]
//   2097152  kT 2MB | 4194304 vT 2MB | 6291456 avT 2MB [k3->k45]
//   8388608  xx 16KB | 8404992 idxb 320KB | 8732672 stats 2KB | 8734720 b1p 2KB
//   8736768  wq/wk/wv frags 6x32KB
//   8933376  wcFhi/lo 2x128KB | 9195520 w2Fhi/lo 2x64KB
//   9326592  xhiF 1MB | 10375168 xloF 1MB
//   11423744 scratch 32MB (topk overflow fallback only)
// ---------------------------------------------------------------------------
#define WS_FULL 44978176u

extern "C" void kernel_launch(void* const* d_in, const int* in_sizes, int n_in,
                              void* d_out, int out_size, void* d_ws, size_t ws_size,
                              hipStream_t stream) {
    fp desc1 = (fp)d_in[0];
    fp wq = (fp)d_in[1];  fp bq = (fp)d_in[2];
    fp wk = (fp)d_in[3];  fp bk = (fp)d_in[4];
    fp wv = (fp)d_in[5];  fp bv = (fp)d_in[6];
    fp wm = (fp)d_in[7];  fp bm = (fp)d_in[8];
    fp w1 = (fp)d_in[9];  fp b1 = (fp)d_in[10];
    fp gamma = (fp)d_in[11]; fp beta = (fp)d_in[12];
    fp w2 = (fp)d_in[13]; fp b2 = (fp)d_in[14];

    if (ws_size < (size_t)WS_FULL) return;  // all-zero out => ws too small

    char* ws = (char*)d_ws;
    float*  qT    = (float*) (ws + 0);
    float*  kT    = (float*) (ws + 2097152);
    float*  vT    = (float*) (ws + 4194304);
    float*  avT   = (float*) (ws + 6291456);
    float*  xx    = (float*) (ws + 8388608);
    int*    idxb  = (int*)   (ws + 8404992);
    float*  stats = (float*) (ws + 8732672);
    float*  b1p   = (float*) (ws + 8734720);
    ushort* wqFhi = (ushort*)(ws + 8736768);
    ushort* wqFlo = (ushort*)(ws + 8769536);
    ushort* wkFhi = (ushort*)(ws + 8802304);
    ushort* wkFlo = (ushort*)(ws + 8835072);
    ushort* wvFhi = (ushort*)(ws + 8867840);
    ushort* wvFlo = (ushort*)(ws + 8900608);
    ushort* wcFhi = (ushort*)(ws + 8933376);
    ushort* wcFlo = (ushort*)(ws + 9064448);
    ushort* w2Fhi = (ushort*)(ws + 9195520);
    ushort* w2Flo = (ushort*)(ws + 9261056);
    ushort* xhiF  = (ushort*)(ws + 9326592);
    ushort* xloF  = (ushort*)(ws + 10375168);
    float*  scratch = (float*)(ws + 11423744);
    float*  outp  = (float*)d_out;

    prep_all<<<835, 256, 0, stream>>>(desc1, wq, wk, wv, wm, w1, w2, bm, b1,
                                      xx, xhiF, xloF,
                                      wqFhi, wqFlo, wkFhi, wkFlo, wvFhi, wvFlo,
                                      wcFhi, wcFlo, w2Fhi, w2Flo, b1p, stats);
    gemm_key_topk<<<256, 1024, 0, stream>>>(xhiF, xloF, xx,
                                            wqFhi, wqFlo, wkFhi, wkFlo,
                                            wvFhi, wvFlo,
                                            bq, bk, bv, qT, kT, vT,
                                            idxb, scratch);
    k3_attn<<<2048, 256, 0, stream>>>(qT, kT, vT, idxb, avT);
    {
        const ushort* xhiFc = xhiF; const ushort* xloFc = xloF;
        const float* avTc = avT;
        const ushort* wcFhic = wcFhi; const ushort* wcFloc = wcFlo;
        const float* b1pc = b1p;
        const ushort* w2Fhic = w2Fhi; const ushort* w2Floc = w2Flo;
        void* args[] = { &xhiFc, &xloFc, &avTc, &wcFhic, &wcFloc,
                         &b1pc, &stats, &gamma, &beta,
                         &w2Fhic, &w2Floc, &b2, &desc1, &outp };
        hipLaunchCooperativeKernel((const void*)k45_fused,
                                   dim3(256), dim3(1024), args, 0, stream);
    }
}

// Round 13
// 149.819 us; speedup vs baseline: 1.3867x; 1.3746x over previous
//
#include <hip/hip_runtime.h>
#include <math.h>

#define NPT 2048
#define KNN 20

typedef const float* fp;
typedef __attribute__((ext_vector_type(4))) float f32x4;
typedef __attribute__((ext_vector_type(8))) short s16x8;

// round-to-nearest-even f32 -> bf16 bits (inputs are finite)
__device__ __forceinline__ ushort f2bf_rne(float v) {
    unsigned u = __float_as_uint(v);
    unsigned r = u + 0x7FFFu + ((u >> 16) & 1u);
    return (ushort)(r >> 16);
}
__device__ __forceinline__ float bfbits2f(ushort h) {
    return __uint_as_float(((unsigned)h) << 16);
}
__device__ __forceinline__ s16x8 ldfrag(const ushort* p) {
    union { uint4 u; s16x8 s; } cv;
    cv.u = *reinterpret_cast<const uint4*>(p);
    return cv.s;
}
// 8 consecutive f32 -> bf16 hi/lo fragment pair (in-register fragify)
__device__ __forceinline__ void f8_hilo(const float* row, s16x8* hi, s16x8* lo) {
    float4 f0 = *reinterpret_cast<const float4*>(row);
    float4 f1 = *reinterpret_cast<const float4*>(row + 4);
    float f[8] = {f0.x, f0.y, f0.z, f0.w, f1.x, f1.y, f1.z, f1.w};
    union { ushort u[8]; s16x8 s; } H, L;
    #pragma unroll
    for (int j = 0; j < 8; j++) {
        ushort h = f2bf_rne(f[j]);
        H.u[j] = h;
        L.u[j] = f2bf_rne(f[j] - bfbits2f(h));
    }
    *hi = H.s; *lo = L.s;
}

// ---------------------------------------------------------------------------
// prep_all: blocks [0,256) = fragify x + xx; blocks [256,835) = weight frags
//   (q/k/v K=128; wc=[w1x | w1a@wm] K=256 on-the-fly; w2 K=256), b1p, stats=0.
// ---------------------------------------------------------------------------
__global__ __launch_bounds__(256) void prep_all(
    fp xbf, fp wq, fp wk, fp wv, fp wm, fp w1, fp w2, fp bm, fp b1,
    float* xx, ushort* xhiF, ushort* xloF,
    ushort* wqFhi, ushort* wqFlo, ushort* wkFhi, ushort* wkFlo,
    ushort* wvFhi, ushort* wvFlo,
    ushort* wcFhi, ushort* wcFlo, ushort* w2Fhi, ushort* w2Flo,
    float* b1p, float* stats) {
    int t = threadIdx.x;
    if (blockIdx.x < 256) {                 // ---- x frags + xx ----
        __shared__ float xs[16][129];
        __shared__ float xpart[16][17];
        int p0 = blockIdx.x * 16;
        int b = p0 >> 11, n0 = p0 & 2047;
        fp xb = xbf + (size_t)b * 128 * NPT;
        {
            int c = t >> 1, half = t & 1;
            float4 f0 = *reinterpret_cast<const float4*>(xb + (size_t)c * NPT + n0 + half * 8);
            float4 f1 = *reinterpret_cast<const float4*>(xb + (size_t)c * NPT + n0 + half * 8 + 4);
            xs[half * 8 + 0][c] = f0.x; xs[half * 8 + 1][c] = f0.y;
            xs[half * 8 + 2][c] = f0.z; xs[half * 8 + 3][c] = f0.w;
            xs[half * 8 + 4][c] = f1.x; xs[half * 8 + 5][c] = f1.y;
            xs[half * 8 + 6][c] = f1.z; xs[half * 8 + 7][c] = f1.w;
        }
        __syncthreads();
        int p = t & 15, g = t >> 4, c0 = g * 8;
        float f[8];
        #pragma unroll
        for (int j = 0; j < 8; j++) f[j] = xs[p][c0 + j];
        float ps = 0.f;
        #pragma unroll
        for (int j = 0; j < 8; j++) ps += f[j] * f[j];
        xpart[p][g] = ps;
        union { ushort u[8]; uint4 q; } H, L;
        #pragma unroll
        for (int j = 0; j < 8; j++) {
            ushort hi = f2bf_rne(f[j]);
            H.u[j] = hi;
            L.u[j] = f2bf_rne(f[j] - bfbits2f(hi));
        }
        size_t off = ((size_t)blockIdx.x * 4 + (c0 >> 5)) * 512
                   + (size_t)(((((c0 >> 3) & 3) * 16) + p) * 8);
        *reinterpret_cast<uint4*>(xhiF + off) = H.q;
        *reinterpret_cast<uint4*>(xloF + off) = L.q;
        __syncthreads();
        if (t < 16) {
            float s = 0.f;
            #pragma unroll
            for (int gg = 0; gg < 16; gg++) s += xpart[t][gg];
            xx[p0 + t] = s;
        }
        return;
    }
    int wid = (blockIdx.x - 256) * 256 + t;
    if (wid < 49152) {                      // q/k/v frags (K=128)
        int which = wid >> 14, e = wid & 16383;
        int lane = (e >> 3) & 63, j = e & 7, kk = (e >> 9) & 3, nt = e >> 11;
        int n = nt * 16 + (lane & 15);
        int k = kk * 32 + (lane >> 4) * 8 + j;
        fp src = which == 0 ? wq : which == 1 ? wk : wv;
        float v = src[n * 128 + k];
        ushort hi = f2bf_rne(v);
        (which == 0 ? wqFhi : which == 1 ? wkFhi : wvFhi)[e] = hi;
        (which == 0 ? wqFlo : which == 1 ? wkFlo : wvFlo)[e] = f2bf_rne(v - bfbits2f(hi));
    } else if (wid < 114688) {              // wc frags (N=256, K=256)
        int e = wid - 49152;
        int j = e & 7, lane = (e >> 3) & 63, kk = (e >> 9) & 7, nt = e >> 12;
        int n = nt * 16 + (lane & 15);
        int k = kk * 32 + (lane >> 4) * 8 + j;
        float v;
        if (k < 128) {
            v = w1[n * 256 + k];
        } else {                            // W[n][k-128] = w1a@wm on the fly
            int c = k - 128;
            float s = 0.f;
            for (int i = 0; i < 128; i += 4) {
                float4 wr = *reinterpret_cast<const float4*>(w1 + n * 256 + 128 + i);
                s += wr.x * wm[(i + 0) * 128 + c];
                s += wr.y * wm[(i + 1) * 128 + c];
                s += wr.z * wm[(i + 2) * 128 + c];
                s += wr.w * wm[(i + 3) * 128 + c];
            }
            v = s;
        }
        ushort hi = f2bf_rne(v);
        wcFhi[e] = hi;
        wcFlo[e] = f2bf_rne(v - bfbits2f(hi));
    } else if (wid < 147456) {              // w2 frags (N=128, K=256)
        int e = wid - 114688;
        int j = e & 7, lane = (e >> 3) & 63, kk = (e >> 9) & 7, nt = e >> 12;
        int n = nt * 16 + (lane & 15);
        int k = kk * 32 + (lane >> 4) * 8 + j;
        float v = w2[n * 256 + k];
        ushort hi = f2bf_rne(v);
        w2Fhi[e] = hi;
        w2Flo[e] = f2bf_rne(v - bfbits2f(hi));
    } else if (wid < 147712) {              // b1p = b1 + w1a@bm
        int o = wid - 147456;
        float s = b1[o];
        for (int i = 0; i < 128; i++)
            s += w1[o * 256 + 128 + i] * bm[i];
        b1p[o] = s;
    } else {                                // BN stats zero (512)
        stats[wid - 147712] = 0.0f;
    }
}

// ---------------------------------------------------------------------------
// gemm_key_topk v8: v7 + IN-KERNEL final selection (sort_topk folded in).
//   All survivors for a row live in this block's LDS, so the final top-20 is
//   computed here: S<=64 (guaranteed S>=20) -> 64-lane KV bitonic sort, lanes
//   63..44 = top-20 by (val desc, idx asc); 64<S<=256 -> exact iterative
//   extract; S>256 -> scratch dump + full scan (never expected).
// ---------------------------------------------------------------------------
#define MERGE(off) { float ov = __shfl_xor(bv, off); int oi = __shfl_xor(bi, off); \
                     if (ov > bv || (ov == bv && oi < bi)) { bv = ov; bi = oi; } }

#define KEYPAIR(C0, D0, D1) { \
    int ct0 = slab * 128 + w * 8 + C0; \
    int ct1 = ct0 + 1; \
    f32x4 a0 = (f32x4){0.f, 0.f, 0.f, 0.f}; \
    f32x4 a1 = (f32x4){0.f, 0.f, 0.f, 0.f}; \
    _Pragma("unroll 2") \
    for (int kk = 0; kk < 4; kk++) { \
        s16x8 ah = ldfrag(Ahi[kk] + lane * 8); \
        s16x8 al = ldfrag(Alo[kk] + lane * 8); \
        s16x8 b0h = ldfrag(xhiF + ((size_t)(ct0 * 4 + kk)) * 512 + lane * 8); \
        s16x8 b0l = ldfrag(xloF + ((size_t)(ct0 * 4 + kk)) * 512 + lane * 8); \
        s16x8 b1h = ldfrag(xhiF + ((size_t)(ct1 * 4 + kk)) * 512 + lane * 8); \
        s16x8 b1l = ldfrag(xloF + ((size_t)(ct1 * 4 + kk)) * 512 + lane * 8); \
        a0 = __builtin_amdgcn_mfma_f32_16x16x32_bf16(ah, b0h, a0, 0, 0, 0); \
        a1 = __builtin_amdgcn_mfma_f32_16x16x32_bf16(ah, b1h, a1, 0, 0, 0); \
        a0 = __builtin_amdgcn_mfma_f32_16x16x32_bf16(al, b0h, a0, 0, 0, 0); \
        a1 = __builtin_amdgcn_mfma_f32_16x16x32_bf16(al, b1h, a1, 0, 0, 0); \
        a0 = __builtin_amdgcn_mfma_f32_16x16x32_bf16(ah, b0l, a0, 0, 0, 0); \
        a1 = __builtin_amdgcn_mfma_f32_16x16x32_bf16(ah, b1l, a1, 0, 0, 0); \
    } \
    float xx0 = xx[slab * 2048 + (w * 8 + C0) * 16 + cl]; \
    float xx1 = xx[slab * 2048 + (w * 8 + C0 + 1) * 16 + cl]; \
    a0[0] = 2.0f * a0[0] - xx0; a0[1] = 2.0f * a0[1] - xx0; \
    a0[2] = 2.0f * a0[2] - xx0; a0[3] = 2.0f * a0[3] - xx0; \
    a1[0] = 2.0f * a1[0] - xx1; a1[1] = 2.0f * a1[1] - xx1; \
    a1[2] = 2.0f * a1[2] - xx1; a1[3] = 2.0f * a1[3] - xx1; \
    D0 = a0; D1 = a1; \
}

__global__ __launch_bounds__(1024, 4) void gemm_key_topk(
    const ushort* xhiF, const ushort* xloF, const float* xx,
    const ushort* wqFhi, const ushort* wqFlo,
    const ushort* wkFhi, const ushort* wkFlo,
    const ushort* wvFhi, const ushort* wvFlo,
    fp bq, fp bk, fp bv_, float* qT, float* kT, float* vT,
    int* idxbuf, float* scratch) {
    __shared__ ushort Ahi[4][512];          // 4 KB  A-frags hi [kk][lane*8]
    __shared__ ushort Alo[4][512];          // 4 KB  A-frags lo
    __shared__ float chm[16][64];           // 4 KB  per-row chunk maxima
    __shared__ float sv[16][256];           // 16 KB survivor values
    __shared__ int   si[16][256];           // 16 KB survivor cols
    __shared__ float Trow[16];
    __shared__ int   rowcnt[16];
    __shared__ int   ovfAll;
    int tt = threadIdx.x, w = tt >> 6, lane = tt & 63;
    int rt = blockIdx.x;                    // row-tile 0..255
    int slab = rt >> 7, rtl = rt & 127;
    int cl = lane & 15, quad = lane >> 4;

    if (tt < 16) rowcnt[tt] = 0;

    // ---- stage A-frags to LDS (512 threads x 16B = 8 KB) ----
    if (tt < 512) {
        int which = tt >> 8, kk = (tt >> 6) & 3, ln = tt & 63;
        const ushort* src = (which ? xloF : xhiF)
                          + ((size_t)(rt * 4 + kk)) * 512 + ln * 8;
        uint4 v = *reinterpret_cast<const uint4*>(src);
        *reinterpret_cast<uint4*>((which ? Alo[kk] : Ahi[kk]) + ln * 8) = v;
    }
    __syncthreads();

    // ---- Phase 1: qkv (24 (mat,nt) pairs; waves 0..11 take 2 each) ----
    if (w < 12) {
        f32x4 acc0 = (f32x4){0.f, 0.f, 0.f, 0.f};
        f32x4 acc1 = (f32x4){0.f, 0.f, 0.f, 0.f};
        int pair0 = w * 2, pair1 = w * 2 + 1;
        int mat0 = pair0 >> 3, nt0 = pair0 & 7;
        int mat1 = pair1 >> 3, nt1 = pair1 & 7;
        const ushort* w0hi = mat0 == 0 ? wqFhi : mat0 == 1 ? wkFhi : wvFhi;
        const ushort* w0lo = mat0 == 0 ? wqFlo : mat0 == 1 ? wkFlo : wvFlo;
        const ushort* w1hi = mat1 == 0 ? wqFhi : mat1 == 1 ? wkFhi : wvFhi;
        const ushort* w1lo = mat1 == 0 ? wqFlo : mat1 == 1 ? wkFlo : wvFlo;
        #pragma unroll 2
        for (int kk = 0; kk < 4; kk++) {
            s16x8 ah = ldfrag(Ahi[kk] + lane * 8);
            s16x8 al = ldfrag(Alo[kk] + lane * 8);
            s16x8 b0h = ldfrag(w0hi + ((size_t)(nt0 * 4 + kk)) * 512 + lane * 8);
            s16x8 b0l = ldfrag(w0lo + ((size_t)(nt0 * 4 + kk)) * 512 + lane * 8);
            s16x8 b1h = ldfrag(w1hi + ((size_t)(nt1 * 4 + kk)) * 512 + lane * 8);
            s16x8 b1l = ldfrag(w1lo + ((size_t)(nt1 * 4 + kk)) * 512 + lane * 8);
            acc0 = __builtin_amdgcn_mfma_f32_16x16x32_bf16(ah, b0h, acc0, 0, 0, 0);
            acc1 = __builtin_amdgcn_mfma_f32_16x16x32_bf16(ah, b1h, acc1, 0, 0, 0);
            acc0 = __builtin_amdgcn_mfma_f32_16x16x32_bf16(al, b0h, acc0, 0, 0, 0);
            acc1 = __builtin_amdgcn_mfma_f32_16x16x32_bf16(al, b1h, acc1, 0, 0, 0);
            acc0 = __builtin_amdgcn_mfma_f32_16x16x32_bf16(ah, b0l, acc0, 0, 0, 0);
            acc1 = __builtin_amdgcn_mfma_f32_16x16x32_bf16(ah, b1l, acc1, 0, 0, 0);
        }
        int p0 = rt * 16;
        {
            fp bias    = mat0 == 0 ? bq : mat0 == 1 ? bk : bv_;
            float* out = mat0 == 0 ? qT : mat0 == 1 ? kT : vT;
            int o = nt0 * 16 + cl;
            float bvv = bias[o];
            #pragma unroll
            for (int r = 0; r < 4; r++)
                out[(size_t)(p0 + quad * 4 + r) * 128 + o] = acc0[r] + bvv;
        }
        {
            fp bias    = mat1 == 0 ? bq : mat1 == 1 ? bk : bv_;
            float* out = mat1 == 0 ? qT : mat1 == 1 ? kT : vT;
            int o = nt1 * 16 + cl;
            float bvv = bias[o];
            #pragma unroll
            for (int r = 0; r < 4; r++)
                out[(size_t)(p0 + quad * 4 + r) * 128 + o] = acc1[r] + bvv;
        }
    }
    __builtin_amdgcn_sched_barrier(0);

    // ---- Phase 2: key GEMM, 8 named regs, 4 ILP-pairs ----
    f32x4 key0, key1, key2, key3, key4, key5, key6, key7;
    KEYPAIR(0, key0, key1)
    __builtin_amdgcn_sched_barrier(0);
    KEYPAIR(2, key2, key3)
    __builtin_amdgcn_sched_barrier(0);
    KEYPAIR(4, key4, key5)
    __builtin_amdgcn_sched_barrier(0);
    KEYPAIR(6, key6, key7)
    __builtin_amdgcn_sched_barrier(0);

    // ---- chunk maxima: chunks of 32 cols (8 c-tiles x 4 cl); 64/row ----
    {
        float m[4];
        #pragma unroll
        for (int r = 0; r < 4; r++) {
            float mm = fmaxf(fmaxf(fmaxf(key0[r], key1[r]), fmaxf(key2[r], key3[r])),
                             fmaxf(fmaxf(key4[r], key5[r]), fmaxf(key6[r], key7[r])));
            mm = fmaxf(mm, __shfl_xor(mm, 1));
            mm = fmaxf(mm, __shfl_xor(mm, 2));
            m[r] = mm;
        }
        if ((cl & 3) == 0) {
            #pragma unroll
            for (int r = 0; r < 4; r++)
                chm[quad * 4 + r][w * 4 + (cl >> 2)] = m[r];
        }
    }
    __syncthreads();

    // ---- per-row threshold: wave w sorts row w's 64 chunk maxima ----
    {
        float bs = chm[w][lane];
        #pragma unroll
        for (int k = 2; k <= 64; k <<= 1) {
            #pragma unroll
            for (int j = k >> 1; j > 0; j >>= 1) {
                float o = __shfl_xor(bs, j);
                bool dirDesc = (lane & k) != 0;
                bool upper   = (lane & j) != 0;
                bs = (upper != dirDesc) ? fmaxf(bs, o) : fminf(bs, o);
            }
        }
        float T = __shfl(bs, 44);           // 20th largest chunk max <= v20
        if (lane == 0) Trow[w] = T;
    }
    __syncthreads();

    // ---- survivor compaction (atomic append per row) ----
    #pragma unroll
    for (int r = 0; r < 4; r++) {
        int row = quad * 4 + r;
        float T = Trow[row];
        float vals[8] = {key0[r], key1[r], key2[r], key3[r],
                         key4[r], key5[r], key6[r], key7[r]};
        #pragma unroll
        for (int c = 0; c < 8; c++) {
            float v = vals[c];
            if (v >= T) {
                int pos = atomicAdd(&rowcnt[row], 1);
                if (pos < 256) {
                    sv[row][pos] = v;
                    si[row][pos] = (w * 8 + c) * 16 + cl;
                }
            }
        }
    }
    __syncthreads();
    if (tt == 0) {
        int o = 0;
        for (int i = 0; i < 16; i++) o |= (rowcnt[i] > 256) ? 1 : 0;
        ovfAll = o;
    }
    __syncthreads();
    int ovf = ovfAll;

    // ---- in-kernel final selection: wave w owns row w ----
    int S = rowcnt[w];
    int rowg = slab * 2048 + rtl * 16 + w;
    if (S <= 64) {                          // common case (S>=20 guaranteed)
        float v; int idx;
        if (lane < S) { v = sv[w][lane]; idx = si[w][lane]; }
        else          { v = -3.4e38f;    idx = 0x7FFFFFFF; }
        // 64-lane KV bitonic, ascending by (val asc, idx desc):
        // lane 63 = greatest by (val desc, idx asc).
        #pragma unroll
        for (int k = 2; k <= 64; k <<= 1) {
            #pragma unroll
            for (int j = k >> 1; j > 0; j >>= 1) {
                float ov = __shfl_xor(v, j); int oi = __shfl_xor(idx, j);
                bool dirDesc = (lane & k) != 0;
                bool upper   = (lane & j) != 0;
                bool takeMax = (upper != dirDesc);
                bool amax = (v > ov) || (v == ov && idx < oi);
                if (takeMax != amax) { v = ov; idx = oi; }
            }
        }
        if (lane >= 44) idxbuf[(size_t)rowg * KNN + (63 - lane)] = idx;
    } else if (S <= 256) {                  // exact iterative extract
        float vl[4]; int il[4];
        #pragma unroll
        for (int s = 0; s < 4; s++) {
            int g = lane + s * 64;
            bool ok = g < S;
            vl[s] = ok ? sv[w][g] : -3.4e38f;
            il[s] = ok ? si[w][g] : 0x7FFFFFFF;
        }
        unsigned removed = 0u;
        for (int iter = 0; iter < KNN; iter++) {
            float bv = -3.4e38f; int bi = 0x7FFFFFFF;
            #pragma unroll
            for (int s = 0; s < 4; s++) {
                bool live = ((removed >> s) & 1u) == 0u;
                if (live && (vl[s] > bv || (vl[s] == bv && il[s] < bi))) {
                    bv = vl[s]; bi = il[s];
                }
            }
            MERGE(32) MERGE(16) MERGE(8) MERGE(4) MERGE(2) MERGE(1)
            if (lane == 0) idxbuf[(size_t)rowg * KNN + iter] = bi;
            #pragma unroll
            for (int s = 0; s < 4; s++)     // indices unique: safe removal
                if (il[s] == bi) removed |= 1u << s;
        }
    }

    // ---- exact overflow fallback (never expected; correctness only) ----
    if (ovf) {
        #pragma unroll
        for (int r = 0; r < 4; r++) {
            float vals[8] = {key0[r], key1[r], key2[r], key3[r],
                             key4[r], key5[r], key6[r], key7[r]};
            #pragma unroll
            for (int c = 0; c < 8; c++)
                scratch[((size_t)rt * 16 + quad * 4 + r) * 2048
                        + (w * 8 + c) * 16 + cl] = vals[c];
        }
        __syncthreads();
        if (rowcnt[w] > 256) {
            const float* rowp = scratch + ((size_t)rt * 16 + w) * 2048;
            float rv[32];
            #pragma unroll
            for (int j = 0; j < 32; j++) rv[j] = rowp[j * 64 + lane];
            unsigned removed = 0u;
            for (int iter = 0; iter < KNN; iter++) {
                float bv = -3.4e38f; int bi = 0;
                #pragma unroll
                for (int sl = 0; sl < 32; sl++) {
                    bool live = ((removed >> sl) & 1u) == 0u;
                    if (live && rv[sl] > bv) { bv = rv[sl]; bi = sl * 64 + lane; }
                }
                MERGE(32) MERGE(16) MERGE(8) MERGE(4) MERGE(2) MERGE(1)
                if (lane == 0) idxbuf[(size_t)rowg * KNN + iter] = bi;
                if ((bi & 63) == lane) removed |= 1u << (bi >> 6);
            }
        }
    }
}

// ---------------------------------------------------------------------------
// k3 v2: sparse mutual-KNN attention, 2 points/block.
//   (a) dot phase processes 2 neighbors/iter with independent shfl chains;
//   (b) den+acc fused into one pass with a single expf per (t,j).
// ---------------------------------------------------------------------------
__global__ __launch_bounds__(256) void k3_attn(
    fp qT, fp kT, fp vT, const int* idxbuf, float* avT) {
    __shared__ float sbuf[2][KNN * 4];
    __shared__ int   mlist[2][KNN];
    __shared__ int   cnt_s[2];
    int tt = threadIdx.x;
    int half = tt >> 7, t = tt & 127;
    int p = blockIdx.x * 2 + half;
    int b = p >> 11, n = p & 2047;
    int bbase = b * NPT;
    int h = t >> 5;

    if ((tt >> 6) == half * 2) {
        int lane = tt & 63;
        bool fl = false; int m = 0;
        if (lane < KNN) {
            m = idxbuf[(size_t)p * KNN + lane] & 2047;
            const int4* mrow = reinterpret_cast<const int4*>(idxbuf + (size_t)(bbase + m) * KNN);
            int4 r0 = mrow[0], r1 = mrow[1], r2 = mrow[2], r3 = mrow[3], r4 = mrow[4];
            fl = (r0.x == n) || (r0.y == n) || (r0.z == n) || (r0.w == n)
              || (r1.x == n) || (r1.y == n) || (r1.z == n) || (r1.w == n)
              || (r2.x == n) || (r2.y == n) || (r2.z == n) || (r2.w == n)
              || (r3.x == n) || (r3.y == n) || (r3.z == n) || (r3.w == n)
              || (r4.x == n) || (r4.y == n) || (r4.z == n) || (r4.w == n);
        }
        unsigned long long mask = __ballot(fl);
        int pos = __popcll(mask & ((1ull << lane) - 1ull));
        if (fl) mlist[half][pos] = m;
        if (lane == 0) cnt_s[half] = (int)__popcll(mask);
    }
    __syncthreads();

    int cnt = cnt_s[half];
    float qv = qT[(size_t)p * 128 + t];
    int jj = 0;
    for (; jj + 1 < cnt; jj += 2) {
        int m0 = mlist[half][jj], m1 = mlist[half][jj + 1];
        float pr0 = qv * kT[(size_t)(bbase + m0) * 128 + t];
        float pr1 = qv * kT[(size_t)(bbase + m1) * 128 + t];
        pr0 += __shfl_xor(pr0, 16); pr1 += __shfl_xor(pr1, 16);
        pr0 += __shfl_xor(pr0, 8);  pr1 += __shfl_xor(pr1, 8);
        pr0 += __shfl_xor(pr0, 4);  pr1 += __shfl_xor(pr1, 4);
        pr0 += __shfl_xor(pr0, 2);  pr1 += __shfl_xor(pr1, 2);
        pr0 += __shfl_xor(pr0, 1);  pr1 += __shfl_xor(pr1, 1);
        if ((t & 31) == 0) {
            sbuf[half][jj * 4 + h]       = pr0 * 0.17677669529663687f;
            sbuf[half][(jj + 1) * 4 + h] = pr1 * 0.17677669529663687f;
        }
    }
    if (jj < cnt) {
        int m = mlist[half][jj];
        float prod = qv * kT[(size_t)(bbase + m) * 128 + t];
        prod += __shfl_xor(prod, 16);
        prod += __shfl_xor(prod, 8);
        prod += __shfl_xor(prod, 4);
        prod += __shfl_xor(prod, 2);
        prod += __shfl_xor(prod, 1);
        if ((t & 31) == 0) sbuf[half][jj * 4 + h] = prod * 0.17677669529663687f;
    }
    __syncthreads();

    float mx = -3.4e38f;
    for (int j = 0; j < cnt; j++) mx = fmaxf(mx, sbuf[half][j * 4 + h]);
    float den = 0.f, accv = 0.f;
    for (int j = 0; j < cnt; j++) {
        float ex = expf(sbuf[half][j * 4 + h] - mx);
        den += ex;
        accv += ex * vT[(size_t)(bbase + mlist[half][j]) * 128 + t];
    }
    float inv = (cnt > 0) ? (1.0f / den) : 0.0f;
    avT[(size_t)p * 128 + t] = accv * inv;
}

// ---------------------------------------------------------------------------
// k4b v2: 256 blocks x 1024 threads (16 waves = 4 waves/SIMD).
//   Staging: waves 0-7 copy x-frags to LDS; waves 8-11 fragify avT once.
//   Compute: wave w owns nt=w.
// ---------------------------------------------------------------------------
__global__ __launch_bounds__(1024) void k4b_h(
    const ushort* xhiF, const ushort* xloF, const float* avT,
    const ushort* wcFhi, const ushort* wcFlo,
    const float* b1p, float* hbuf, float* stats) {
    __shared__ ushort AH[8][512];           // 8 KB  A-frags hi [kk][lane*8]
    __shared__ ushort AL[8][512];           // 8 KB  A-frags lo
    int tt = threadIdx.x, w = tt >> 6, lane = tt & 63;
    int rt = blockIdx.x;                    // 0..255
    int p0 = rt * 16;

    // ---- stage A-frags (x part: copy; av part: fragify once) ----
    if (w < 8) {
        int which = w & 1, kk = w >> 1;
        const ushort* src = (which ? xloF : xhiF)
                          + ((size_t)(rt * 4 + kk)) * 512 + lane * 8;
        uint4 v = *reinterpret_cast<const uint4*>(src);
        *reinterpret_cast<uint4*>((which ? AL[kk] : AH[kk]) + lane * 8) = v;
    } else if (w < 12) {
        int kk = 4 + (w - 8);
        const float* arow = avT + (size_t)(p0 + (lane & 15)) * 128
                          + (kk - 4) * 32 + (lane >> 4) * 8;
        s16x8 hi, lo;
        f8_hilo(arow, &hi, &lo);
        union { s16x8 s; uint4 u; } cvh, cvl;
        cvh.s = hi; cvl.s = lo;
        *reinterpret_cast<uint4*>(AH[kk] + lane * 8) = cvh.u;
        *reinterpret_cast<uint4*>(AL[kk] + lane * 8) = cvl.u;
    }
    __syncthreads();

    // ---- compute: wave w owns nt = w ----
    int nt = w;
    f32x4 acc = (f32x4){0.f, 0.f, 0.f, 0.f};
    for (int kk = 0; kk < 8; kk++) {
        s16x8 ahi = ldfrag(AH[kk] + lane * 8);
        s16x8 alo = ldfrag(AL[kk] + lane * 8);
        s16x8 bhi = ldfrag(wcFhi + ((size_t)(nt * 8 + kk)) * 512 + lane * 8);
        s16x8 blo = ldfrag(wcFlo + ((size_t)(nt * 8 + kk)) * 512 + lane * 8);
        acc = __builtin_amdgcn_mfma_f32_16x16x32_bf16(ahi, bhi, acc, 0, 0, 0);
        acc = __builtin_amdgcn_mfma_f32_16x16x32_bf16(alo, bhi, acc, 0, 0, 0);
        acc = __builtin_amdgcn_mfma_f32_16x16x32_bf16(ahi, blo, acc, 0, 0, 0);
    }

    int cl = lane & 15, quad = lane >> 4;
    int o = nt * 16 + cl;
    float bb = b1p[o];
    float s = 0.f, s2 = 0.f;
    #pragma unroll
    for (int r = 0; r < 4; r++) {
        float v = acc[r] + bb;
        hbuf[(size_t)(p0 + quad * 4 + r) * 256 + o] = v;
        s += v; s2 += v * v;
    }
    s  += __shfl_xor(s, 16);  s  += __shfl_xor(s, 32);
    s2 += __shfl_xor(s2, 16); s2 += __shfl_xor(s2, 32);
    if (quad == 0) {
        atomicAdd(&stats[o], s);
        atomicAdd(&stats[256 + o], s2);
    }
}

// ---------------------------------------------------------------------------
// k5b v2: 256 blocks x 512 threads (8 waves = 2 waves/SIMD).
//   Staging: wave w BN+relu+fragifies kk=w once into LDS. Compute: wave w
//   owns nt=w.
// ---------------------------------------------------------------------------
__global__ __launch_bounds__(512) void k5b_out(
    const float* hbuf, const float* stats, fp gamma, fp beta,
    const ushort* w2Fhi, const ushort* w2Flo,
    fp b2, fp xbf, float* out) {
    __shared__ ushort HH[8][512];           // 8 KB  h-frags hi [kk][lane*8]
    __shared__ ushort HL[8][512];           // 8 KB  h-frags lo
    int tt = threadIdx.x, w = tt >> 6, lane = tt & 63;
    int rt = blockIdx.x;                    // 0..255
    int p0 = rt * 16;

    // ---- stage: wave w converts kk = w (BN + relu + hi/lo fragify) ----
    {
        int kk = w;
        int c0 = kk * 32 + (lane >> 4) * 8;
        const float* hrow = hbuf + (size_t)(p0 + (lane & 15)) * 256 + c0;
        float4 f0 = *reinterpret_cast<const float4*>(hrow);
        float4 f1 = *reinterpret_cast<const float4*>(hrow + 4);
        float4 s0 = *reinterpret_cast<const float4*>(stats + c0);
        float4 s1 = *reinterpret_cast<const float4*>(stats + c0 + 4);
        float4 q0 = *reinterpret_cast<const float4*>(stats + 256 + c0);
        float4 q1 = *reinterpret_cast<const float4*>(stats + 256 + c0 + 4);
        float4 g0 = *reinterpret_cast<const float4*>(gamma + c0);
        float4 g1 = *reinterpret_cast<const float4*>(gamma + c0 + 4);
        float4 e0 = *reinterpret_cast<const float4*>(beta + c0);
        float4 e1 = *reinterpret_cast<const float4*>(beta + c0 + 4);
        float f[8] = {f0.x, f0.y, f0.z, f0.w, f1.x, f1.y, f1.z, f1.w};
        float sm[8] = {s0.x, s0.y, s0.z, s0.w, s1.x, s1.y, s1.z, s1.w};
        float sq[8] = {q0.x, q0.y, q0.z, q0.w, q1.x, q1.y, q1.z, q1.w};
        float gm[8] = {g0.x, g0.y, g0.z, g0.w, g1.x, g1.y, g1.z, g1.w};
        float bt[8] = {e0.x, e0.y, e0.z, e0.w, e1.x, e1.y, e1.z, e1.w};
        union { ushort u[8]; uint4 q; } H, L;
        #pragma unroll
        for (int j = 0; j < 8; j++) {
            float mu  = sm[j] * (1.0f / 4096.0f);
            float var = fmaxf(sq[j] * (1.0f / 4096.0f) - mu * mu, 0.0f);
            float a    = gm[j] / sqrtf(var + 1e-5f);
            float cadd = bt[j] - mu * a;
            float v = fmaxf(f[j] * a + cadd, 0.0f);
            ushort hi = f2bf_rne(v);
            H.u[j] = hi;
            L.u[j] = f2bf_rne(v - bfbits2f(hi));
        }
        *reinterpret_cast<uint4*>(HH[kk] + lane * 8) = H.q;
        *reinterpret_cast<uint4*>(HL[kk] + lane * 8) = L.q;
    }
    __syncthreads();

    // ---- compute: wave w owns nt = w ----
    int nt = w;
    f32x4 acc = (f32x4){0.f, 0.f, 0.f, 0.f};
    for (int kk = 0; kk < 8; kk++) {
        s16x8 ahi = ldfrag(HH[kk] + lane * 8);
        s16x8 alo = ldfrag(HL[kk] + lane * 8);
        s16x8 bhi = ldfrag(w2Fhi + ((size_t)(nt * 8 + kk)) * 512 + lane * 8);
        s16x8 blo = ldfrag(w2Flo + ((size_t)(nt * 8 + kk)) * 512 + lane * 8);
        acc = __builtin_amdgcn_mfma_f32_16x16x32_bf16(ahi, bhi, acc, 0, 0, 0);
        acc = __builtin_amdgcn_mfma_f32_16x16x32_bf16(alo, bhi, acc, 0, 0, 0);
        acc = __builtin_amdgcn_mfma_f32_16x16x32_bf16(ahi, blo, acc, 0, 0, 0);
    }
    int cl = lane & 15, quad = lane >> 4;
    int b = p0 >> 11, n0 = p0 & 2047;
    int o = nt * 16 + cl;
    float bb = b2[o];
    size_t base = (size_t)b * 128 * NPT + (size_t)o * NPT + n0 + quad * 4;
    float4 xv = *reinterpret_cast<const float4*>(xbf + base);
    float4 ov;
    ov.x = acc[0] + bb + xv.x;
    ov.y = acc[1] + bb + xv.y;
    ov.z = acc[2] + bb + xv.z;
    ov.w = acc[3] + bb + xv.w;
    *reinterpret_cast<float4*>(out + base) = ov;
}

// ---------------------------------------------------------------------------
// Workspace layout (44,978,176 B; scratch only touched on topk overflow):
//   0        qT 2MB [gemm->k3]  <- hbuf 4MB (k4b->k5b) aliases qT+kT
//   2097152  kT 2MB | 4194304 vT 2MB | 6291456 avT 2MB [k3->k4b]
//   8388608  xx 16KB | 8404992 idxb 320KB | 8732672 stats 2KB | 8734720 b1p 2KB
//   8736768  wq/wk/wv frags 6x32KB
//   8933376  wcFhi/lo 2x128KB | 9195520 w2Fhi/lo 2x64KB
//   9326592  xhiF 1MB | 10375168 xloF 1MB
//   11423744 scratch 32MB (topk overflow fallback only)
// ---------------------------------------------------------------------------
#define WS_FULL 44978176u

extern "C" void kernel_launch(void* const* d_in, const int* in_sizes, int n_in,
                              void* d_out, int out_size, void* d_ws, size_t ws_size,
                              hipStream_t stream) {
    fp desc1 = (fp)d_in[0];
    fp wq = (fp)d_in[1];  fp bq = (fp)d_in[2];
    fp wk = (fp)d_in[3];  fp bk = (fp)d_in[4];
    fp wv = (fp)d_in[5];  fp bv = (fp)d_in[6];
    fp wm = (fp)d_in[7];  fp bm = (fp)d_in[8];
    fp w1 = (fp)d_in[9];  fp b1 = (fp)d_in[10];
    fp gamma = (fp)d_in[11]; fp beta = (fp)d_in[12];
    fp w2 = (fp)d_in[13]; fp b2 = (fp)d_in[14];

    if (ws_size < (size_t)WS_FULL) return;  // all-zero out => ws too small

    char* ws = (char*)d_ws;
    float*  qT    = (float*) (ws + 0);
    float*  kT    = (float*) (ws + 2097152);
    float*  vT    = (float*) (ws + 4194304);
    float*  avT   = (float*) (ws + 6291456);
    float*  xx    = (float*) (ws + 8388608);
    int*    idxb  = (int*)   (ws + 8404992);
    float*  stats = (float*) (ws + 8732672);
    float*  b1p   = (float*) (ws + 8734720);
    ushort* wqFhi = (ushort*)(ws + 8736768);
    ushort* wqFlo = (ushort*)(ws + 8769536);
    ushort* wkFhi = (ushort*)(ws + 8802304);
    ushort* wkFlo = (ushort*)(ws + 8835072);
    ushort* wvFhi = (ushort*)(ws + 8867840);
    ushort* wvFlo = (ushort*)(ws + 8900608);
    ushort* wcFhi = (ushort*)(ws + 8933376);
    ushort* wcFlo = (ushort*)(ws + 9064448);
    ushort* w2Fhi = (ushort*)(ws + 9195520);
    ushort* w2Flo = (ushort*)(ws + 9261056);
    ushort* xhiF  = (ushort*)(ws + 9326592);
    ushort* xloF  = (ushort*)(ws + 10375168);
    float*  scratch = (float*)(ws + 11423744);
    float*  hbuf  = (float*) (ws + 0);      // aliases qT+kT (dead after k3)

    prep_all<<<835, 256, 0, stream>>>(desc1, wq, wk, wv, wm, w1, w2, bm, b1,
                                      xx, xhiF, xloF,
                                      wqFhi, wqFlo, wkFhi, wkFlo, wvFhi, wvFlo,
                                      wcFhi, wcFlo, w2Fhi, w2Flo, b1p, stats);
    gemm_key_topk<<<256, 1024, 0, stream>>>(xhiF, xloF, xx,
                                            wqFhi, wqFlo, wkFhi, wkFlo,
                                            wvFhi, wvFlo,
                                            bq, bk, bv, qT, kT, vT,
                                            idxb, scratch);
    k3_attn<<<2048, 256, 0, stream>>>(qT, kT, vT, idxb, avT);
    k4b_h<<<256, 1024, 0, stream>>>(xhiF, xloF, avT, wcFhi, wcFlo,
                                    b1p, hbuf, stats);
    k5b_out<<<256, 512, 0, stream>>>(hbuf, stats, gamma, beta, w2Fhi, w2Flo,
                                     b2, desc1, (float*)d_out);
}